// Round 1
// baseline (274.868 us; speedup 1.0000x reference)
//
#include <hip/hip_runtime.h>
#include <hip/hip_bf16.h>
#include <stdint.h>

#define SEQ 4096
#define DM  1024

typedef __attribute__((ext_vector_type(8))) short bf16x8;
typedef __attribute__((ext_vector_type(4))) float f32x4;

__device__ __forceinline__ short f2bf(float f) {
  union { float f; unsigned int i; } x; x.f = f;
  unsigned int r = x.i + 0x7FFFu + ((x.i >> 16) & 1u);
  return (short)(r >> 16);
}

__device__ __forceinline__ void gload16(const short* g, short* l) {
  __builtin_amdgcn_global_load_lds(
      (const __attribute__((address_space(1))) unsigned int*)g,
      (__attribute__((address_space(3))) unsigned int*)l, 16, 0, 0);
}

__device__ __forceinline__ float wave_max(float v) {
#pragma unroll
  for (int o = 32; o; o >>= 1) v = fmaxf(v, __shfl_xor(v, o));
  return v;
}
__device__ __forceinline__ float wave_sum(float v) {
#pragma unroll
  for (int o = 32; o; o >>= 1) v += __shfl_xor(v, o);
  return v;
}

// C[M,N] = A[M,K](bf16,row-major) * B[N,K](bf16,row-major)^T  (+ epilogue)
// EPI: 0=none, 1=+bias[col], 2=*scale then mask -> -inf, 3=+resid[row,col]
// OUTF: write fp32 to Cf; OUTB: write bf16 to Cb
template <int EPI, int OUTF, int OUTB>
__global__ __launch_bounds__(256) void gemm_nt(
    const short* __restrict__ A, const short* __restrict__ B,
    float* __restrict__ Cf, short* __restrict__ Cb,
    const float* __restrict__ bias, const int* __restrict__ mask,
    const float* __restrict__ resid, int M, int N, int K, float scale) {
  __shared__ short lds[2][2][128 * 32];
  const int tid = threadIdx.x;
  const int lane = tid & 63;
  const int wid = tid >> 6;
  const int wr = wid >> 1, wc = wid & 1;
  const int m0 = blockIdx.y * 128, n0 = blockIdx.x * 128;

  f32x4 acc[4][4];
#pragma unroll
  for (int i = 0; i < 4; i++)
#pragma unroll
    for (int j = 0; j < 4; j++) acc[i][j] = (f32x4){0.f, 0.f, 0.f, 0.f};

  const int sr = tid >> 2;           // staging row 0..63
  const int sc = (tid & 3) * 8;      // staging col (shorts)
  const short* gA0 = A + (long)(m0 + sr) * K + sc;
  const short* gA1 = A + (long)(m0 + 64 + sr) * K + sc;
  const short* gB0 = B + (long)(n0 + sr) * K + sc;
  const short* gB1 = B + (long)(n0 + 64 + sr) * K + sc;
  const int wbase = (tid & 192) << 3;  // wave-uniform LDS base (shorts)

  auto stage = [&](int buf, int kt) {
    const int ko = kt << 5;
    short* la = &lds[buf][0][0] + wbase;
    short* lb = &lds[buf][1][0] + wbase;
    gload16(gA0 + ko, la);
    gload16(gA1 + ko, la + 2048);
    gload16(gB0 + ko, lb);
    gload16(gB1 + ko, lb + 2048);
  };

  const int fr = lane & 15;
  const int fko = (lane >> 4) << 3;

  auto compute = [&](int buf) {
    const short* la = &lds[buf][0][0];
    const short* lb = &lds[buf][1][0];
    bf16x8 af[4], bg[4];
#pragma unroll
    for (int m = 0; m < 4; m++)
      af[m] = *(const bf16x8*)(la + ((wr * 64 + m * 16 + fr) << 5) + fko);
#pragma unroll
    for (int n = 0; n < 4; n++)
      bg[n] = *(const bf16x8*)(lb + ((wc * 64 + n * 16 + fr) << 5) + fko);
#pragma unroll
    for (int m = 0; m < 4; m++)
#pragma unroll
      for (int n = 0; n < 4; n++)
        acc[m][n] = __builtin_amdgcn_mfma_f32_16x16x32_bf16(af[m], bg[n],
                                                            acc[m][n], 0, 0, 0);
  };

  const int NK = K >> 5;
  stage(0, 0);
  asm volatile("s_waitcnt vmcnt(0)" ::: "memory");
  __syncthreads();
  int cur = 0;
  for (int kt = 1; kt < NK; ++kt) {
    stage(cur ^ 1, kt);
    compute(cur);
    asm volatile("s_waitcnt vmcnt(0)" ::: "memory");
    __syncthreads();
    cur ^= 1;
  }
  compute(cur);

  const int fq = lane >> 4;
#pragma unroll
  for (int m = 0; m < 4; m++) {
#pragma unroll
    for (int n = 0; n < 4; n++) {
      const int col = n0 + wc * 64 + n * 16 + fr;
      float bcol = 0.f;
      if (EPI == 1) bcol = bias[col];
#pragma unroll
      for (int r = 0; r < 4; r++) {
        const int row = m0 + wr * 64 + m * 16 + fq * 4 + r;
        float v = acc[m][n][r];
        if (EPI == 1) v += bcol;
        if (EPI == 2) {
          v *= scale;
          if (mask[(long)row * N + col]) v = -INFINITY;
        }
        if (EPI == 3) v += resid[(long)row * N + col];
        const long off = (long)row * N + col;
        if (OUTF) Cf[off] = v;
        if (OUTB) Cb[off] = f2bf(v);
      }
    }
  }
}

__global__ __launch_bounds__(256) void cvt_f32_to_bf16(
    const float* __restrict__ in, short* __restrict__ out, int n4) {
  int i = blockIdx.x * 256 + threadIdx.x;
  if (i < n4) {
    float4 f = ((const float4*)in)[i];
    short4 o;
    o.x = f2bf(f.x); o.y = f2bf(f.y); o.z = f2bf(f.z); o.w = f2bf(f.w);
    ((short4*)out)[i] = o;
  }
}

// in[R][C] fp32 -> out[C][R] bf16
__global__ void transpose_w(const float* __restrict__ in,
                            short* __restrict__ out, int R, int C) {
  __shared__ float tile[32][33];
  const int bx = blockIdx.x * 32;  // C dim
  const int by = blockIdx.y * 32;  // R dim
  const int tx = threadIdx.x, ty = threadIdx.y;
#pragma unroll
  for (int i = 0; i < 32; i += 8)
    tile[ty + i][tx] = in[(long)(by + ty + i) * C + bx + tx];
  __syncthreads();
#pragma unroll
  for (int i = 0; i < 32; i += 8)
    out[(long)(bx + ty + i) * R + by + tx] = f2bf(tile[tx][ty + i]);
}

// in[R][C] bf16 -> out[C][R] bf16
__global__ void transpose_b(const short* __restrict__ in,
                            short* __restrict__ out, int R, int C) {
  __shared__ short tile[32][33];
  const int bx = blockIdx.x * 32;
  const int by = blockIdx.y * 32;
  const int tx = threadIdx.x, ty = threadIdx.y;
#pragma unroll
  for (int i = 0; i < 32; i += 8)
    tile[ty + i][tx] = in[(long)(by + ty + i) * C + bx + tx];
  __syncthreads();
#pragma unroll
  for (int i = 0; i < 32; i += 8)
    out[(long)(bx + ty + i) * R + by + tx] = tile[tx][ty + i];
}

__global__ __launch_bounds__(256) void softmax_rows(float* __restrict__ sc,
                                                    short* __restrict__ pb) {
  const long row = blockIdx.x;
  float* p = sc + row * (long)SEQ;
  short* pbr = pb + row * (long)SEQ;
  const int tid = threadIdx.x;
  const int wid = tid >> 6, lane = tid & 63;
  float v[16];
  float mx = -INFINITY;
#pragma unroll
  for (int i = 0; i < 16; i++) {
    v[i] = p[tid + 256 * i];
    mx = fmaxf(mx, v[i]);
  }
  mx = wave_max(mx);
  __shared__ float red[4];
  if (lane == 0) red[wid] = mx;
  __syncthreads();
  mx = fmaxf(fmaxf(red[0], red[1]), fmaxf(red[2], red[3]));
  float sum = 0.f;
#pragma unroll
  for (int i = 0; i < 16; i++) {
    v[i] = __expf(v[i] - mx);
    sum += v[i];
  }
  sum = wave_sum(sum);
  __shared__ float red2[4];
  if (lane == 0) red2[wid] = sum;
  __syncthreads();
  sum = red2[0] + red2[1] + red2[2] + red2[3];
  const float inv = 1.0f / sum;
#pragma unroll
  for (int i = 0; i < 16; i++) {
    float pv = v[i] * inv;
    p[tid + 256 * i] = pv;
    pbr[tid + 256 * i] = f2bf(pv);
  }
}

__global__ __launch_bounds__(256) void layernorm_rows(
    float* __restrict__ h, const float* __restrict__ gamma,
    const float* __restrict__ beta) {
  const long row = blockIdx.x;
  float* p = h + row * (long)DM;
  const int tid = threadIdx.x;
  const int wid = tid >> 6, lane = tid & 63;
  float v[4];
  float s = 0.f;
#pragma unroll
  for (int i = 0; i < 4; i++) {
    v[i] = p[tid + 256 * i];
    s += v[i];
  }
  s = wave_sum(s);
  __shared__ float red[4];
  if (lane == 0) red[wid] = s;
  __syncthreads();
  const float mu = (red[0] + red[1] + red[2] + red[3]) * (1.f / DM);
  float var = 0.f;
#pragma unroll
  for (int i = 0; i < 4; i++) {
    float d = v[i] - mu;
    var += d * d;
  }
  var = wave_sum(var);
  __shared__ float red2[4];
  if (lane == 0) red2[wid] = var;
  __syncthreads();
  var = (red2[0] + red2[1] + red2[2] + red2[3]) * (1.f / DM);
  const float inv = rsqrtf(var + 1e-5f);
#pragma unroll
  for (int i = 0; i < 4; i++) {
    int c = tid + 256 * i;
    p[c] = (v[i] - mu) * inv * gamma[c] + beta[c];
  }
}

extern "C" void kernel_launch(void* const* d_in, const int* in_sizes, int n_in,
                              void* d_out, int out_size, void* d_ws,
                              size_t ws_size, hipStream_t stream) {
  const float* x    = (const float*)d_in[0];
  const int* mask   = (const int*)d_in[1];
  const float* wq   = (const float*)d_in[2];
  const float* bq   = (const float*)d_in[3];
  const float* wk   = (const float*)d_in[4];
  const float* bk   = (const float*)d_in[5];
  const float* wv   = (const float*)d_in[6];
  const float* bv   = (const float*)d_in[7];
  const float* wo   = (const float*)d_in[8];
  const float* bo   = (const float*)d_in[9];
  const float* gamma = (const float*)d_in[10];
  const float* beta  = (const float*)d_in[11];

  float* out  = (float*)d_out;          // h, then LayerNorm in-place [4096*1024]
  float* attn = out + 4194304;          // scores, then softmax in-place [4096*4096]

  char* w = (char*)d_ws;
  short* xb    = (short*)(w + 0);
  short* qb    = (short*)(w + 8388608);
  short* kb    = (short*)(w + 16777216);
  short* vb    = (short*)(w + 25165824);
  short* attnb = (short*)(w + 0);       // aliases xb..vb (dead by then)
  short* vT    = (short*)(w + 33554432);
  short* cb    = (short*)(w + 41943040);
  short* wqT   = (short*)(w + 50331648);
  short* wkT   = (short*)(w + 52428800);
  short* wvT   = (short*)(w + 54525952);
  short* woT   = (short*)(w + 56623104);

  // x -> bf16
  cvt_f32_to_bf16<<<4096, 256, 0, stream>>>(x, xb, 1048576);
  // weights: [K,N] fp32 -> [N,K] bf16
  dim3 tb(32, 8);
  transpose_w<<<dim3(32, 32), tb, 0, stream>>>(wq, wqT, 1024, 1024);
  transpose_w<<<dim3(32, 32), tb, 0, stream>>>(wk, wkT, 1024, 1024);
  transpose_w<<<dim3(32, 32), tb, 0, stream>>>(wv, wvT, 1024, 1024);
  transpose_w<<<dim3(32, 32), tb, 0, stream>>>(wo, woT, 1024, 1024);

  dim3 gqkv(DM / 128, SEQ / 128);  // (8,32)
  gemm_nt<1, 0, 1><<<gqkv, 256, 0, stream>>>(xb, wqT, nullptr, qb, bq, nullptr,
                                             nullptr, SEQ, DM, DM, 1.f);
  gemm_nt<1, 0, 1><<<gqkv, 256, 0, stream>>>(xb, wkT, nullptr, kb, bk, nullptr,
                                             nullptr, SEQ, DM, DM, 1.f);
  gemm_nt<1, 0, 1><<<gqkv, 256, 0, stream>>>(xb, wvT, nullptr, vb, bv, nullptr,
                                             nullptr, SEQ, DM, DM, 1.f);
  // v^T for the AV gemm (B operand wants [N,K] = [1024,4096])
  transpose_b<<<dim3(32, 128), tb, 0, stream>>>(vb, vT, 4096, 1024);

  // scores = mask(q k^T / 8) -> fp32 into d_out attention region
  dim3 gss(SEQ / 128, SEQ / 128);  // (32,32)
  gemm_nt<2, 1, 0><<<gss, 256, 0, stream>>>(qb, kb, attn, nullptr, nullptr,
                                            mask, nullptr, SEQ, SEQ, DM, 0.125f);
  // softmax in-place + bf16 copy
  softmax_rows<<<SEQ, 256, 0, stream>>>(attn, attnb);

  // context = P v + x -> bf16
  dim3 gav(DM / 128, SEQ / 128);
  gemm_nt<3, 0, 1><<<gav, 256, 0, stream>>>(attnb, vT, nullptr, cb, nullptr,
                                            nullptr, x, SEQ, DM, SEQ, 1.f);
  // h = context wo + bo -> fp32 into d_out
  gemm_nt<1, 1, 0><<<gav, 256, 0, stream>>>(cb, woT, out, nullptr, bo, nullptr,
                                            nullptr, SEQ, DM, DM, 1.f);
  // LayerNorm in-place
  layernorm_rows<<<SEQ, 256, 0, stream>>>(out, gamma, beta);
}

// Round 2
// 251.093 us; speedup vs baseline: 1.0947x; 1.0947x over previous
//
#include <hip/hip_runtime.h>
#include <hip/hip_bf16.h>
#include <stdint.h>

#define SEQ 4096
#define DM  1024

typedef __attribute__((ext_vector_type(8))) short bf16x8;
typedef __attribute__((ext_vector_type(4))) float f32x4;

__device__ __forceinline__ short f2bf(float f) {
  union { float f; unsigned int i; } x; x.f = f;
  unsigned int r = x.i + 0x7FFFu + ((x.i >> 16) & 1u);
  return (short)(r >> 16);
}
__device__ __forceinline__ float bf2f(short s) {
  union { unsigned int i; float f; } u;
  u.i = ((unsigned int)(unsigned short)s) << 16;
  return u.f;
}

__device__ __forceinline__ void gload16(const short* g, short* l) {
  __builtin_amdgcn_global_load_lds(
      (const __attribute__((address_space(1))) unsigned int*)g,
      (__attribute__((address_space(3))) unsigned int*)l, 16, 0, 0);
}

__device__ __forceinline__ float wave_max(float v) {
#pragma unroll
  for (int o = 32; o; o >>= 1) v = fmaxf(v, __shfl_xor(v, o));
  return v;
}
__device__ __forceinline__ float wave_sum(float v) {
#pragma unroll
  for (int o = 32; o; o >>= 1) v += __shfl_xor(v, o);
  return v;
}

// C[M,N] = A[M,K]*B[N,K]^T, bf16 in, fp32 acc. 128x128 tile, BK=32, 4 waves.
// 3-buffer LDS pipeline with counted vmcnt(4) + raw s_barrier (loads stay in
// flight across the barrier; no full drain in steady state).
// EPI: 0=none, 1=+bias[col], 2=v*scale then mask->bf16 -inf
// SPLIT=2: grid doubled; split s takes K-range [s*K, s*K+K), writes Cb(s=0)/Cb2(s=1)
template <int EPI, int OUTF, int OUTB, int SPLIT>
__global__ __launch_bounds__(256) void gemm_nt(
    const short* __restrict__ A, const short* __restrict__ B,
    float* __restrict__ Cf, short* __restrict__ Cb, short* __restrict__ Cb2,
    const float* __restrict__ bias, const int* __restrict__ mask,
    int K, int lda, int ldb, int ldc, float scale, int ntiles, int maskld) {
  __shared__ short lds[3][2][4096];  // 48 KiB: 3 bufs x (A,B) x 128x32
  const int nwg = gridDim.x;
  const int bid = blockIdx.x;
  int wg = (bid & 7) * (nwg >> 3) + (bid >> 3);  // XCD-chunked swizzle
  int split = 0;
  if (SPLIT == 2) { split = wg & 1; wg >>= 1; }
  const int m0 = (wg / ntiles) * 128, n0 = (wg % ntiles) * 128;
  if (SPLIT == 2) { A += (long)split * K; B += (long)split * K; }

  const int tid = threadIdx.x;
  const int lane = tid & 63;
  const int wid = tid >> 6;
  const int wr = wid >> 1, wc = wid & 1;

  f32x4 acc[4][4];
#pragma unroll
  for (int i = 0; i < 4; i++)
#pragma unroll
    for (int j = 0; j < 4; j++) acc[i][j] = (f32x4){0.f, 0.f, 0.f, 0.f};

  const int sr = tid >> 2;        // staging row 0..63
  const int sc = (tid & 3) * 8;   // staging col (shorts)
  const short* gA0 = A + (long)(m0 + sr) * lda + sc;
  const short* gA1 = A + (long)(m0 + 64 + sr) * lda + sc;
  const short* gB0 = B + (long)(n0 + sr) * ldb + sc;
  const short* gB1 = B + (long)(n0 + 64 + sr) * ldb + sc;
  const int wbase = (tid & 192) << 3;  // wave-uniform LDS base (shorts)

  auto stage = [&](int buf, int kt) {
    const int ko = kt << 5;
    short* la = &lds[buf][0][0] + wbase;
    short* lb = &lds[buf][1][0] + wbase;
    gload16(gA0 + ko, la);
    gload16(gA1 + ko, la + 2048);
    gload16(gB0 + ko, lb);
    gload16(gB1 + ko, lb + 2048);
  };

  const int fr = lane & 15;
  const int fko = (lane >> 4) << 3;

  auto compute = [&](int buf) {
    const short* la = &lds[buf][0][0];
    const short* lb = &lds[buf][1][0];
    bf16x8 af[4], bg[4];
#pragma unroll
    for (int m = 0; m < 4; m++)
      af[m] = *(const bf16x8*)(la + ((wr * 64 + m * 16 + fr) << 5) + fko);
#pragma unroll
    for (int n = 0; n < 4; n++)
      bg[n] = *(const bf16x8*)(lb + ((wc * 64 + n * 16 + fr) << 5) + fko);
#pragma unroll
    for (int m = 0; m < 4; m++)
#pragma unroll
      for (int n = 0; n < 4; n++)
        acc[m][n] = __builtin_amdgcn_mfma_f32_16x16x32_bf16(af[m], bg[n],
                                                            acc[m][n], 0, 0, 0);
  };

  const int NK = K >> 5;  // NK >= 2 always here
  stage(0, 0);
  stage(1, 1);
  int kt = 0;
  for (; kt < NK - 1; ++kt) {
    asm volatile("s_waitcnt vmcnt(4)" ::: "memory");  // own stage(kt) landed
    __builtin_amdgcn_s_barrier();                      // all waves' stage(kt) landed,
    asm volatile("" ::: "memory");                     // all passed compute(kt-1)
    if (kt + 2 < NK) stage((kt + 2) % 3, kt + 2);      // overwrites buf of kt-1: safe
    compute(kt % 3);
  }
  asm volatile("s_waitcnt vmcnt(0)" ::: "memory");
  __builtin_amdgcn_s_barrier();
  asm volatile("" ::: "memory");
  compute(kt % 3);

  short* Co = (SPLIT == 2 && split) ? Cb2 : Cb;
  const int fq = lane >> 4;
#pragma unroll
  for (int m = 0; m < 4; m++) {
#pragma unroll
    for (int n = 0; n < 4; n++) {
      const int col = n0 + wc * 64 + n * 16 + fr;
      float bcol = 0.f;
      if (EPI == 1) bcol = bias[col];
#pragma unroll
      for (int r = 0; r < 4; r++) {
        const int row = m0 + wr * 64 + m * 16 + fq * 4 + r;
        const long off = (long)row * ldc + col;
        float v = acc[m][n][r];
        if (EPI == 1) v += bcol;
        if (EPI == 2) {
          v *= scale;
          short sv = mask[(long)row * maskld + col] ? (short)0xFF80 : f2bf(v);
          Co[off] = sv;
          continue;
        }
        if (OUTF) Cf[off] = v;
        if (OUTB) Co[off] = f2bf(v);
      }
    }
  }
}

__global__ __launch_bounds__(256) void cvt_f32_to_bf16(
    const float* __restrict__ in, short* __restrict__ out, int n4) {
  int i = blockIdx.x * 256 + threadIdx.x;
  if (i < n4) {
    float4 f = ((const float4*)in)[i];
    short4 o;
    o.x = f2bf(f.x); o.y = f2bf(f.y); o.z = f2bf(f.z); o.w = f2bf(f.w);
    ((short4*)out)[i] = o;
  }
}

// in[R][C] fp32 -> out[C][R] bf16 (out row stride = R)
__global__ void transpose_w(const float* __restrict__ in,
                            short* __restrict__ out, int R, int C) {
  __shared__ float tile[32][33];
  const int bx = blockIdx.x * 32;
  const int by = blockIdx.y * 32;
  const int tx = threadIdx.x, ty = threadIdx.y;
#pragma unroll
  for (int i = 0; i < 32; i += 8)
    tile[ty + i][tx] = in[(long)(by + ty + i) * C + bx + tx];
  __syncthreads();
#pragma unroll
  for (int i = 0; i < 32; i += 8)
    out[(long)(bx + ty + i) * R + by + tx] = f2bf(tile[tx][ty + i]);
}

// in[R][C] bf16 (row stride ldin) -> out[C][R] bf16
__global__ void transpose_b_ld(const short* __restrict__ in,
                               short* __restrict__ out, int R, int C, int ldin) {
  __shared__ short tile[32][33];
  const int bx = blockIdx.x * 32;
  const int by = blockIdx.y * 32;
  const int tx = threadIdx.x, ty = threadIdx.y;
#pragma unroll
  for (int i = 0; i < 32; i += 8)
    tile[ty + i][tx] = in[(long)(by + ty + i) * ldin + bx + tx];
  __syncthreads();
#pragma unroll
  for (int i = 0; i < 32; i += 8)
    out[(long)(bx + ty + i) * R + by + tx] = tile[tx][ty + i];
}

// row softmax over masked bf16 scores -> bf16 probs
__global__ __launch_bounds__(256) void softmax_rows(const short* __restrict__ Sb,
                                                    short* __restrict__ Pb) {
  const long row = blockIdx.x;
  const bf16x8* src = (const bf16x8*)(Sb + row * SEQ);
  bf16x8* dst = (bf16x8*)(Pb + row * SEQ);
  const int tid = threadIdx.x;
  const int wid = tid >> 6, lane = tid & 63;
  bf16x8 a = src[tid], b = src[tid + 256];
  float v[16];
#pragma unroll
  for (int j = 0; j < 8; j++) { v[j] = bf2f(a[j]); v[8 + j] = bf2f(b[j]); }
  float mx = -INFINITY;
#pragma unroll
  for (int j = 0; j < 16; j++) mx = fmaxf(mx, v[j]);
  mx = wave_max(mx);
  __shared__ float red[4];
  if (lane == 0) red[wid] = mx;
  __syncthreads();
  mx = fmaxf(fmaxf(red[0], red[1]), fmaxf(red[2], red[3]));
  float sum = 0.f;
#pragma unroll
  for (int j = 0; j < 16; j++) {
    v[j] = __expf(v[j] - mx);
    sum += v[j];
  }
  sum = wave_sum(sum);
  __shared__ float red2[4];
  if (lane == 0) red2[wid] = sum;
  __syncthreads();
  sum = red2[0] + red2[1] + red2[2] + red2[3];
  const float inv = 1.0f / sum;
  bf16x8 o0, o1;
#pragma unroll
  for (int j = 0; j < 8; j++) {
    o0[j] = f2bf(v[j] * inv);
    o1[j] = f2bf(v[8 + j] * inv);
  }
  dst[tid] = o0;
  dst[tid + 256] = o1;
}

// attention fp32 output = expand of bf16 probs
__global__ __launch_bounds__(256) void expand_bf16_f32(
    const short* __restrict__ in, float* __restrict__ out) {
  long i = (long)blockIdx.x * 256 + threadIdx.x;
  bf16x8 a = ((const bf16x8*)in)[i];
  float4 lo, hi;
  lo.x = bf2f(a[0]); lo.y = bf2f(a[1]); lo.z = bf2f(a[2]); lo.w = bf2f(a[3]);
  hi.x = bf2f(a[4]); hi.y = bf2f(a[5]); hi.z = bf2f(a[6]); hi.w = bf2f(a[7]);
  ((float4*)out)[2 * i] = lo;
  ((float4*)out)[2 * i + 1] = hi;
}

// context = pav0 + pav1 + x -> bf16
__global__ __launch_bounds__(256) void reduce_ctx(
    const short* __restrict__ p0, const short* __restrict__ p1,
    const float* __restrict__ x, short* __restrict__ cb) {
  long i = (long)blockIdx.x * 256 + threadIdx.x;
  bf16x8 a = ((const bf16x8*)p0)[i];
  bf16x8 b = ((const bf16x8*)p1)[i];
  float4 x0 = ((const float4*)x)[2 * i];
  float4 x1 = ((const float4*)x)[2 * i + 1];
  float xs[8] = {x0.x, x0.y, x0.z, x0.w, x1.x, x1.y, x1.z, x1.w};
  bf16x8 o;
#pragma unroll
  for (int j = 0; j < 8; j++) o[j] = f2bf(bf2f(a[j]) + bf2f(b[j]) + xs[j]);
  ((bf16x8*)cb)[i] = o;
}

__global__ __launch_bounds__(256) void layernorm_rows(
    float* __restrict__ h, const float* __restrict__ gamma,
    const float* __restrict__ beta) {
  const long row = blockIdx.x;
  float* p = h + row * (long)DM;
  const int tid = threadIdx.x;
  const int wid = tid >> 6, lane = tid & 63;
  float v[4];
  float s = 0.f;
#pragma unroll
  for (int i = 0; i < 4; i++) {
    v[i] = p[tid + 256 * i];
    s += v[i];
  }
  s = wave_sum(s);
  __shared__ float red[4];
  if (lane == 0) red[wid] = s;
  __syncthreads();
  const float mu = (red[0] + red[1] + red[2] + red[3]) * (1.f / DM);
  float var = 0.f;
#pragma unroll
  for (int i = 0; i < 4; i++) {
    float d = v[i] - mu;
    var += d * d;
  }
  var = wave_sum(var);
  __shared__ float red2[4];
  if (lane == 0) red2[wid] = var;
  __syncthreads();
  var = (red2[0] + red2[1] + red2[2] + red2[3]) * (1.f / DM);
  const float inv = rsqrtf(var + 1e-5f);
#pragma unroll
  for (int i = 0; i < 4; i++) {
    int c = tid + 256 * i;
    p[c] = (v[i] - mu) * inv * gamma[c] + beta[c];
  }
}

extern "C" void kernel_launch(void* const* d_in, const int* in_sizes, int n_in,
                              void* d_out, int out_size, void* d_ws,
                              size_t ws_size, hipStream_t stream) {
  const float* x    = (const float*)d_in[0];
  const int* mask   = (const int*)d_in[1];
  const float* wq   = (const float*)d_in[2];
  const float* bq   = (const float*)d_in[3];
  const float* wk   = (const float*)d_in[4];
  const float* bk   = (const float*)d_in[5];
  const float* wv   = (const float*)d_in[6];
  const float* bv   = (const float*)d_in[7];
  const float* wo   = (const float*)d_in[8];
  const float* bo   = (const float*)d_in[9];
  const float* gamma = (const float*)d_in[10];
  const float* beta  = (const float*)d_in[11];

  float* out  = (float*)d_out;           // h / final output [4096*1024] fp32
  float* attn = out + 4194304;           // attention [4096*4096] fp32
  short* Sb   = (short*)attn;            // masked bf16 scores (lower 32 MiB)
  short* pav0 = (short*)out;             // AV partial 0 (bf16, 8 MiB of h region)

  // ws layout (MiB): woT[0,2) wqkvT[2,8) xb[8,16) qkv[16,40) vT[40,48)
  //                  attnb[8,40) (after qkv dead)  cb[40,48) (after vT dead)
  //                  pav1[48,56)  bqkv aliases [48,..) during QKV only
  char* w = (char*)d_ws;
  short* woT   = (short*)(w + 0);
  short* wqkvT = (short*)(w + 2097152);
  short* xb    = (short*)(w + 8388608);
  short* qkv   = (short*)(w + 16777216);
  short* vT    = (short*)(w + 41943040);
  short* attnb = (short*)(w + 8388608);
  short* cb    = (short*)(w + 41943040);
  short* pav1  = (short*)(w + 50331648);
  float* bqkv  = (float*)(w + 50331648);

  // ---- prep: bf16 casts / transposes / bias concat ----
  cvt_f32_to_bf16<<<4096, 256, 0, stream>>>(x, xb, 1048576);
  dim3 tb(32, 8);
  transpose_w<<<dim3(32, 32), tb, 0, stream>>>(wq, wqkvT, 1024, 1024);
  transpose_w<<<dim3(32, 32), tb, 0, stream>>>(wk, wqkvT + 1048576, 1024, 1024);
  transpose_w<<<dim3(32, 32), tb, 0, stream>>>(wv, wqkvT + 2097152, 1024, 1024);
  transpose_w<<<dim3(32, 32), tb, 0, stream>>>(wo, woT, 1024, 1024);
  hipMemcpyAsync(bqkv, bq, 4096, hipMemcpyDeviceToDevice, stream);
  hipMemcpyAsync(bqkv + 1024, bk, 4096, hipMemcpyDeviceToDevice, stream);
  hipMemcpyAsync(bqkv + 2048, bv, 4096, hipMemcpyDeviceToDevice, stream);

  // ---- qkv = x @ [wq|wk|wv] + b : one GEMM, N=3072 ----
  gemm_nt<1, 0, 1, 1><<<768, 256, 0, stream>>>(
      xb, wqkvT, nullptr, qkv, nullptr, bqkv, nullptr,
      1024, 1024, 1024, 3072, 1.f, 24, 0);

  // v^T [1024][4096] from qkv's v-part (strided)
  transpose_b_ld<<<dim3(32, 128), tb, 0, stream>>>(qkv + 2048, vT, 4096, 1024, 3072);

  // ---- scores: masked bf16 q k^T / 8 -> Sb (in d_out attn region) ----
  gemm_nt<2, 0, 1, 1><<<1024, 256, 0, stream>>>(
      qkv, qkv + 1024, nullptr, Sb, nullptr, nullptr, mask,
      1024, 3072, 3072, 4096, 0.125f, 32, 4096);

  // ---- softmax -> bf16 probs ----
  softmax_rows<<<SEQ, 256, 0, stream>>>(Sb, attnb);

  // ---- AV split-K=2: partials bf16 ----
  gemm_nt<0, 0, 1, 2><<<512, 256, 0, stream>>>(
      attnb, vT, nullptr, pav0, pav1, nullptr, nullptr,
      2048, 4096, 4096, 1024, 1.f, 8, 0);

  // context = pav0 + pav1 + x -> bf16
  reduce_ctx<<<2048, 256, 0, stream>>>(pav0, pav1, x, cb);

  // ---- h = context @ wo + bo (fp32 into d_out) ----
  gemm_nt<1, 1, 0, 1><<<256, 256, 0, stream>>>(
      cb, woT, out, nullptr, nullptr, bo, nullptr,
      1024, 1024, 1024, 1024, 1.f, 8, 0);

  // ---- LayerNorm in place ----
  layernorm_rows<<<SEQ, 256, 0, stream>>>(out, gamma, beta);

  // ---- attention fp32 output (overwrites Sb region) ----
  expand_bf16_f32<<<8192, 256, 0, stream>>>(attnb, attn);
}

// Round 4
// 239.782 us; speedup vs baseline: 1.1463x; 1.0472x over previous
//
#include <hip/hip_runtime.h>
#include <hip/hip_bf16.h>
#include <stdint.h>

#define SEQ 4096
#define DM  1024

typedef __attribute__((ext_vector_type(8))) short bf16x8;
typedef __attribute__((ext_vector_type(4))) float f32x4;

template <int V> struct Int { static constexpr int v = V; };

__device__ __forceinline__ short f2bf(float f) {
  union { float f; unsigned int i; } x; x.f = f;
  unsigned int r = x.i + 0x7FFFu + ((x.i >> 16) & 1u);
  return (short)(r >> 16);
}
__device__ __forceinline__ float bf2f(short s) {
  union { unsigned int i; float f; } u;
  u.i = ((unsigned int)(unsigned short)s) << 16;
  return u.f;
}

__device__ __forceinline__ void gload16(const short* g, short* l) {
  __builtin_amdgcn_global_load_lds(
      (const __attribute__((address_space(1))) unsigned int*)g,
      (__attribute__((address_space(3))) unsigned int*)l, 16, 0, 0);
}

__device__ __forceinline__ float wave_max(float v) {
#pragma unroll
  for (int o = 32; o; o >>= 1) v = fmaxf(v, __shfl_xor(v, o));
  return v;
}
__device__ __forceinline__ float wave_sum(float v) {
#pragma unroll
  for (int o = 32; o; o >>= 1) v += __shfl_xor(v, o);
  return v;
}

#define BARRIER() do { asm volatile("" ::: "memory"); \
  __builtin_amdgcn_s_barrier(); asm volatile("" ::: "memory"); } while (0)
#define MF(a, b, c) __builtin_amdgcn_mfma_f32_16x16x32_bf16(a, b, c, 0, 0, 0)

// ---------------------------------------------------------------------------
// 256x256-tile 8-phase bf16 GEMM (m201-style): C[M,N] = A[M,K] * B[N,K]^T
// 8 waves (2M x 4N), BK=64, 128 KiB LDS (2 buf x {A0,A1,B0,B1} x 16 KiB),
// st_16x32 XOR swizzle (pre-swizzled gload source + swizzled ds_read).
// EXACTLY one half-tile staged per phase; counted vmcnt(4) at phases 4 & 8.
// Steady-state ledger (loads, 2 per stage): at ph4 tail the queue is
// [B(1,*,t+1)x4, A(1,*,t+1)x4, B(0,*,t+2)x4] = 12 -> vmcnt(4) drains the 8
// that form buf1; at ph8 tail [B(0,*)x4, A(0,*)x4, B(1,*)x4] = 12 -> vmcnt(4)
// drains the 8 that form buf0. Prologue matches (12 outstanding, vmcnt(4)).
// Final iteration (nl=false): ph4 has only 8 outstanding -> vmcnt(0).
// EPI: 0 = plain bf16 out, 1 = +bias[col] bf16 out, 2 = *scale + mask -> -inf
// split-K: grid = ntm*ntn*nsplit; split s reads K-range [s*Ksplit,(s+1)*Ksplit)
//          and writes C + s*csplit.
// ---------------------------------------------------------------------------
template <int EPI>
__global__ __launch_bounds__(512, 2) void gemm8(
    const short* __restrict__ A, const short* __restrict__ B,
    short* __restrict__ C, const float* __restrict__ bias,
    const int* __restrict__ mask, int Ksplit, int lda, int ldb, int ldc,
    float scale, int ntm, int ntn, long csplit, int maskld) {
  __shared__ short lds[2][4][8192];  // [buf][A0,A1,B0,B1][128 rows x 64 k]
  const int tid = threadIdx.x;
  const int lane = tid & 63;
  const int wid = tid >> 6;   // 0..7
  const int wr = wid >> 2;    // 0,1  -> A slot / output row half
  const int wc = wid & 3;     // 0..3 -> 64-col group
  const int bid = blockIdx.x, nwg = gridDim.x;
  int wg = (bid & 7) * (nwg >> 3) + (bid >> 3);  // XCD-chunked swizzle
  const int tpg = ntm * ntn;
  const int split = wg / tpg;
  wg -= split * tpg;
  const int m0 = (wg / ntn) * 256;
  const int n0 = (wg % ntn) * 256;
  const short* Ab = A + (long)split * Ksplit;
  const short* Bb = B + (long)split * Ksplit;
  short* Co = C + (long)split * csplit;

  // staging: thread t covers LDS bytes [t*16, t*16+16) of a half-tile (linear
  // dest required by global_load_lds); source address pre-swizzled (involution
  // swz: flip byte-bit5 iff byte-bit9) so ds_read applies the same XOR.
  const int o0 = tid * 16;
  const int oo = o0 ^ (((o0 >> 9) & 1) << 5);
  const int sr0 = oo >> 7;           // source row 0..63
  const int sc0 = (oo & 127) >> 1;   // source col in shorts (8-mult)

  auto stA = [&](int buf, int h, int kt) {
    const short* g = Ab + (long)(m0 + h * 128 + sr0) * lda + kt * 64 + sc0;
    short* l = &lds[buf][h][0] + wid * 512;
    gload16(g, l);
    gload16(g + (long)64 * lda, l + 4096);
  };
  auto stB = [&](int buf, int h, int kt) {
    const short* g = Bb + (long)(n0 + h * 128 + sr0) * ldb + kt * 64 + sc0;
    short* l = &lds[buf][2 + h][0] + wid * 512;
    gload16(g, l);
    gload16(g + (long)64 * ldb, l + 4096);
  };

  const int ll = lane & 15, lh = lane >> 4;
  auto ldaf = [&](int buf, int c, int mm, int kk) {
    const int r = c * 32 + mm * 16 + ll;
    const int off = (r * 64 + kk * 32 + lh * 8) ^ (((r >> 2) & 1) << 4);
    return *(const bf16x8*)(&lds[buf][wr][0] + off);
  };
  auto ldbf = [&](int buf, int n, int kk) {
    const int r = (wc & 1) * 64 + n * 16 + ll;
    const int off = (r * 64 + kk * 32 + lh * 8) ^ (((r >> 2) & 1) << 4);
    return *(const bf16x8*)(&lds[buf][2 + (wc >> 1)][0] + off);
  };

  f32x4 acc[8][4];
#pragma unroll
  for (int i = 0; i < 8; i++)
#pragma unroll
    for (int j = 0; j < 4; j++) acc[i][j] = (f32x4){0.f, 0.f, 0.f, 0.f};
  bf16x8 Bf[4][2];

  const int NT = Ksplit >> 6;  // even for all call sites (16,16,16,4)
  // prologue: B(0,*,0), A(0,*,0), B(1,*,1) = 12 loads; vmcnt(4) drains buf0.
  stB(0, 0, 0); stB(0, 1, 0);
  stA(0, 0, 0); stA(0, 1, 0);
  stB(1, 0, 1); stB(1, 1, 1);
  asm volatile("s_waitcnt vmcnt(4)" ::: "memory");
  BARRIER();

  auto phase = [&](auto BUF, auto CC, auto LB, auto&& stg, auto&& tail) {
    constexpr int buf = decltype(BUF)::v;
    constexpr int c = decltype(CC)::v;
    if constexpr (decltype(LB)::v != 0) {
#pragma unroll
      for (int n = 0; n < 4; n++) {
        Bf[n][0] = ldbf(buf, n, 0);
        Bf[n][1] = ldbf(buf, n, 1);
      }
    }
    bf16x8 a00 = ldaf(buf, c, 0, 0), a01 = ldaf(buf, c, 0, 1);
    bf16x8 a10 = ldaf(buf, c, 1, 0), a11 = ldaf(buf, c, 1, 1);
    stg();
    BARRIER();
    __builtin_amdgcn_s_setprio(1);
#pragma unroll
    for (int n = 0; n < 4; n++) {
      acc[2 * c][n] = MF(a00, Bf[n][0], acc[2 * c][n]);
      acc[2 * c][n] = MF(a01, Bf[n][1], acc[2 * c][n]);
      acc[2 * c + 1][n] = MF(a10, Bf[n][0], acc[2 * c + 1][n]);
      acc[2 * c + 1][n] = MF(a11, Bf[n][1], acc[2 * c + 1][n]);
    }
    __builtin_amdgcn_s_setprio(0);
    tail();
    BARRIER();
  };

  for (int t = 0; t < NT; t += 2) {
    const bool nl = (t + 2 < NT);
    // phases 1-4: tile t (buf0); stage A(1,*,t+1), B(0,*,t+2)
    phase(Int<0>{}, Int<0>{}, Int<1>{}, [&] { stA(1, 0, t + 1); }, [] {});
    phase(Int<0>{}, Int<1>{}, Int<0>{}, [&] { stA(1, 1, t + 1); }, [] {});
    phase(Int<0>{}, Int<2>{}, Int<0>{}, [&] { if (nl) stB(0, 0, t + 2); },
          [] {});
    phase(Int<0>{}, Int<3>{}, Int<0>{}, [&] { if (nl) stB(0, 1, t + 2); },
          [&] {
            if (nl) { asm volatile("s_waitcnt vmcnt(4)" ::: "memory"); }
            else    { asm volatile("s_waitcnt vmcnt(0)" ::: "memory"); }
          });
    // phases 5-8: tile t+1 (buf1); stage A(0,*,t+2), B(1,*,t+3)
    phase(Int<1>{}, Int<0>{}, Int<1>{}, [&] { if (nl) stA(0, 0, t + 2); },
          [] {});
    phase(Int<1>{}, Int<1>{}, Int<0>{}, [&] { if (nl) stA(0, 1, t + 2); },
          [] {});
    phase(Int<1>{}, Int<2>{}, Int<0>{}, [&] { if (nl) stB(1, 0, t + 3); },
          [] {});
    phase(Int<1>{}, Int<3>{}, Int<0>{}, [&] { if (nl) stB(1, 1, t + 3); },
          [&] {
            if (nl) { asm volatile("s_waitcnt vmcnt(4)" ::: "memory"); }
            else    { asm volatile("s_waitcnt vmcnt(0)" ::: "memory"); }
          });
  }

  // epilogue: wave writes 128x64 at (m0 + wr*128, n0 + wc*64)
  const int rb = m0 + wr * 128 + lh * 4;
  const int cb0 = n0 + wc * 64 + ll;
#pragma unroll
  for (int mi = 0; mi < 8; mi++) {
#pragma unroll
    for (int n = 0; n < 4; n++) {
      const int col = cb0 + n * 16;
      float bv = 0.f;
      if (EPI == 1) bv = bias[col];
#pragma unroll
      for (int r = 0; r < 4; r++) {
        const int row = rb + mi * 16 + r;
        const long off = (long)row * ldc + col;
        float v = acc[mi][n][r];
        if (EPI == 1) v += bv;
        if (EPI == 2) {
          v *= scale;
          if (mask[(long)row * maskld + col]) { Co[off] = (short)0xFF80; continue; }
        }
        Co[off] = f2bf(v);
      }
    }
  }
}

// ---------------------------------------------------------------------------

__global__ __launch_bounds__(256) void cvt_f32_to_bf16(
    const float* __restrict__ in, short* __restrict__ out, int n4) {
  int i = blockIdx.x * 256 + threadIdx.x;
  if (i < n4) {
    float4 f = ((const float4*)in)[i];
    short4 o;
    o.x = f2bf(f.x); o.y = f2bf(f.y); o.z = f2bf(f.z); o.w = f2bf(f.w);
    ((short4*)out)[i] = o;
  }
}

// in[R][C] fp32 -> out[C][R] bf16
__global__ void transpose_w(const float* __restrict__ in,
                            short* __restrict__ out, int R, int C) {
  __shared__ float tile[32][33];
  const int bx = blockIdx.x * 32;
  const int by = blockIdx.y * 32;
  const int tx = threadIdx.x, ty = threadIdx.y;
#pragma unroll
  for (int i = 0; i < 32; i += 8)
    tile[ty + i][tx] = in[(long)(by + ty + i) * C + bx + tx];
  __syncthreads();
#pragma unroll
  for (int i = 0; i < 32; i += 8)
    out[(long)(bx + ty + i) * R + by + tx] = f2bf(tile[tx][ty + i]);
}

// in[R][C] bf16 (row stride ldin) -> out[C][R] bf16
__global__ void transpose_b_ld(const short* __restrict__ in,
                               short* __restrict__ out, int R, int C, int ldin) {
  __shared__ short tile[32][33];
  const int bx = blockIdx.x * 32;
  const int by = blockIdx.y * 32;
  const int tx = threadIdx.x, ty = threadIdx.y;
#pragma unroll
  for (int i = 0; i < 32; i += 8)
    tile[ty + i][tx] = in[(long)(by + ty + i) * ldin + bx + tx];
  __syncthreads();
#pragma unroll
  for (int i = 0; i < 32; i += 8)
    out[(long)(bx + ty + i) * R + by + tx] = tile[tx][ty + i];
}

// row softmax over masked bf16 scores -> bf16 probs
__global__ __launch_bounds__(256) void softmax_rows(const short* __restrict__ Sb,
                                                    short* __restrict__ Pb) {
  const long row = blockIdx.x;
  const bf16x8* src = (const bf16x8*)(Sb + row * SEQ);
  bf16x8* dst = (bf16x8*)(Pb + row * SEQ);
  const int tid = threadIdx.x;
  const int wid = tid >> 6, lane = tid & 63;
  bf16x8 a = src[tid], b = src[tid + 256];
  float v[16];
#pragma unroll
  for (int j = 0; j < 8; j++) { v[j] = bf2f(a[j]); v[8 + j] = bf2f(b[j]); }
  float mx = -INFINITY;
#pragma unroll
  for (int j = 0; j < 16; j++) mx = fmaxf(mx, v[j]);
  mx = wave_max(mx);
  __shared__ float red[4];
  if (lane == 0) red[wid] = mx;
  __syncthreads();
  mx = fmaxf(fmaxf(red[0], red[1]), fmaxf(red[2], red[3]));
  float sum = 0.f;
#pragma unroll
  for (int j = 0; j < 16; j++) {
    v[j] = __expf(v[j] - mx);
    sum += v[j];
  }
  sum = wave_sum(sum);
  __shared__ float red2[4];
  if (lane == 0) red2[wid] = sum;
  __syncthreads();
  sum = red2[0] + red2[1] + red2[2] + red2[3];
  const float inv = 1.0f / sum;
  bf16x8 o0, o1;
#pragma unroll
  for (int j = 0; j < 8; j++) {
    o0[j] = f2bf(v[j] * inv);
    o1[j] = f2bf(v[8 + j] * inv);
  }
  dst[tid] = o0;
  dst[tid + 256] = o1;
}

// attention fp32 output = expand of bf16 probs
__global__ __launch_bounds__(256) void expand_bf16_f32(
    const short* __restrict__ in, float* __restrict__ out) {
  long i = (long)blockIdx.x * 256 + threadIdx.x;
  bf16x8 a = ((const bf16x8*)in)[i];
  float4 lo, hi;
  lo.x = bf2f(a[0]); lo.y = bf2f(a[1]); lo.z = bf2f(a[2]); lo.w = bf2f(a[3]);
  hi.x = bf2f(a[4]); hi.y = bf2f(a[5]); hi.z = bf2f(a[6]); hi.w = bf2f(a[7]);
  ((float4*)out)[2 * i] = lo;
  ((float4*)out)[2 * i + 1] = hi;
}

// context = sum of 4 AV partials + x -> bf16
__global__ __launch_bounds__(256) void reduce_ctx4(
    const short* __restrict__ p, const float* __restrict__ x,
    short* __restrict__ cb) {
  const long i = (long)blockIdx.x * 256 + threadIdx.x;
  bf16x8 a = ((const bf16x8*)p)[i];
  bf16x8 b = ((const bf16x8*)(p + 4194304))[i];
  bf16x8 c = ((const bf16x8*)(p + 8388608))[i];
  bf16x8 d = ((const bf16x8*)(p + 12582912))[i];
  float4 x0 = ((const float4*)x)[2 * i];
  float4 x1 = ((const float4*)x)[2 * i + 1];
  float xs[8] = {x0.x, x0.y, x0.z, x0.w, x1.x, x1.y, x1.z, x1.w};
  bf16x8 o;
#pragma unroll
  for (int j = 0; j < 8; j++)
    o[j] = f2bf(bf2f(a[j]) + bf2f(b[j]) + bf2f(c[j]) + bf2f(d[j]) + xs[j]);
  ((bf16x8*)cb)[i] = o;
}

// LayerNorm fused with the 4-way out-proj split reduce + bias.
__global__ __launch_bounds__(256) void ln4(
    const short* __restrict__ ph, const float* __restrict__ bo,
    const float* __restrict__ gamma, const float* __restrict__ beta,
    float* __restrict__ out) {
  const long row = blockIdx.x;
  const int tid = threadIdx.x;
  const int wid = tid >> 6, lane = tid & 63;
  const long base = row * DM + tid * 4;
  short4 p0 = *(const short4*)(ph + base);
  short4 p1 = *(const short4*)(ph + 4194304 + base);
  short4 p2 = *(const short4*)(ph + 8388608 + base);
  short4 p3 = *(const short4*)(ph + 12582912 + base);
  float4 bb = *(const float4*)(bo + tid * 4);
  float v[4];
  v[0] = bf2f(p0.x) + bf2f(p1.x) + bf2f(p2.x) + bf2f(p3.x) + bb.x;
  v[1] = bf2f(p0.y) + bf2f(p1.y) + bf2f(p2.y) + bf2f(p3.y) + bb.y;
  v[2] = bf2f(p0.z) + bf2f(p1.z) + bf2f(p2.z) + bf2f(p3.z) + bb.z;
  v[3] = bf2f(p0.w) + bf2f(p1.w) + bf2f(p2.w) + bf2f(p3.w) + bb.w;
  float s = v[0] + v[1] + v[2] + v[3];
  s = wave_sum(s);
  __shared__ float red[4];
  if (lane == 0) red[wid] = s;
  __syncthreads();
  const float mu = (red[0] + red[1] + red[2] + red[3]) * (1.f / DM);
  float var = 0.f;
#pragma unroll
  for (int j = 0; j < 4; j++) {
    float d = v[j] - mu;
    var += d * d;
  }
  var = wave_sum(var);
  __shared__ float red2[4];
  if (lane == 0) red2[wid] = var;
  __syncthreads();
  var = (red2[0] + red2[1] + red2[2] + red2[3]) * (1.f / DM);
  const float inv = rsqrtf(var + 1e-5f);
  float4 g = *(const float4*)(gamma + tid * 4);
  float4 be = *(const float4*)(beta + tid * 4);
  float4 o;
  o.x = (v[0] - mu) * inv * g.x + be.x;
  o.y = (v[1] - mu) * inv * g.y + be.y;
  o.z = (v[2] - mu) * inv * g.z + be.z;
  o.w = (v[3] - mu) * inv * g.w + be.w;
  *(float4*)(out + base) = o;
}

extern "C" void kernel_launch(void* const* d_in, const int* in_sizes, int n_in,
                              void* d_out, int out_size, void* d_ws,
                              size_t ws_size, hipStream_t stream) {
  const float* x    = (const float*)d_in[0];
  const int* mask   = (const int*)d_in[1];
  const float* wq   = (const float*)d_in[2];
  const float* bq   = (const float*)d_in[3];
  const float* wk   = (const float*)d_in[4];
  const float* bk   = (const float*)d_in[5];
  const float* wv   = (const float*)d_in[6];
  const float* bv   = (const float*)d_in[7];
  const float* wo   = (const float*)d_in[8];
  const float* bo   = (const float*)d_in[9];
  const float* gamma = (const float*)d_in[10];
  const float* beta  = (const float*)d_in[11];

  float* out  = (float*)d_out;             // final output [4096*1024] fp32
  float* attn = out + 4194304;             // attention [4096*4096] fp32
  short* Sb   = (short*)attn;              // masked bf16 scores (32 MiB, dead after softmax)
  short* pav  = (short*)attn;              // 4 AV partials (32 MiB, over Sb)
  short* ph   = (short*)(attn + 8388608);  // 4 out-proj partials (32 MiB)
  short* cbuf = (short*)out;               // context bf16 (8 MiB, dead before LN writes)

  // ws (MiB): wqkvT[0,6) woT[6,8) xb[8,16) qkv[16,40) vT[40,48) bqkv[48,+12K)
  //           attnb[8,40) aliases xb+qkv once both are dead
  char* w = (char*)d_ws;
  short* wqkvT = (short*)(w + 0);
  short* woT   = (short*)(w + 6291456);
  short* xb    = (short*)(w + 8388608);
  short* qkv   = (short*)(w + 16777216);
  short* attnb = (short*)(w + 8388608);
  short* vT    = (short*)(w + 41943040);
  float* bqkv  = (float*)(w + 50331648);

  // ---- prep ----
  cvt_f32_to_bf16<<<4096, 256, 0, stream>>>(x, xb, 1048576);
  dim3 tb(32, 8);
  transpose_w<<<dim3(32, 32), tb, 0, stream>>>(wq, wqkvT, 1024, 1024);
  transpose_w<<<dim3(32, 32), tb, 0, stream>>>(wk, wqkvT + 1048576, 1024, 1024);
  transpose_w<<<dim3(32, 32), tb, 0, stream>>>(wv, wqkvT + 2097152, 1024, 1024);
  transpose_w<<<dim3(32, 32), tb, 0, stream>>>(wo, woT, 1024, 1024);
  hipMemcpyAsync(bqkv, bq, 4096, hipMemcpyDeviceToDevice, stream);
  hipMemcpyAsync(bqkv + 1024, bk, 4096, hipMemcpyDeviceToDevice, stream);
  hipMemcpyAsync(bqkv + 2048, bv, 4096, hipMemcpyDeviceToDevice, stream);

  // ---- qkv = x @ [wq|wk|wv] + b : M=4096 N=3072 K=1024, 192 blocks ----
  gemm8<1><<<192, 512, 0, stream>>>(xb, wqkvT, qkv, bqkv, nullptr,
                                    1024, 1024, 1024, 3072, 1.f, 16, 12, 0, 0);

  // v^T [1024][4096] from qkv's v-part
  transpose_b_ld<<<dim3(32, 128), tb, 0, stream>>>(qkv + 2048, vT, 4096, 1024, 3072);

  // ---- scores: masked bf16 (q k^T)/8 -> Sb : 256 blocks ----
  gemm8<2><<<256, 512, 0, stream>>>(qkv, qkv + 1024, Sb, nullptr, mask,
                                    1024, 3072, 3072, 4096, 0.125f, 16, 16, 0, 4096);

  // ---- softmax -> bf16 probs ----
  softmax_rows<<<SEQ, 256, 0, stream>>>(Sb, attnb);

  // ---- AV split-K=4 -> 4 bf16 partials (over Sb region) : 256 blocks ----
  gemm8<0><<<256, 512, 0, stream>>>(attnb, vT, pav, nullptr, nullptr,
                                    1024, 4096, 4096, 1024, 1.f, 16, 4,
                                    4194304L, 0);

  // context = sum partials + x -> bf16
  reduce_ctx4<<<2048, 256, 0, stream>>>(pav, x, cbuf);

  // ---- out-proj split-K=4 -> 4 bf16 partials : 256 blocks ----
  gemm8<0><<<256, 512, 0, stream>>>(cbuf, woT, ph, nullptr, nullptr,
                                    256, 1024, 1024, 1024, 1.f, 16, 4,
                                    4194304L, 0);

  // ---- LayerNorm fused with partial-reduce + bias ----
  ln4<<<SEQ, 256, 0, stream>>>(ph, bo, gamma, beta, out);

  // ---- attention fp32 output (after everything that uses the attn region) --
  expand_bf16_f32<<<8192, 256, 0, stream>>>(attnb, attn);
}

// Round 5
// 214.022 us; speedup vs baseline: 1.2843x; 1.1204x over previous
//
#include <hip/hip_runtime.h>
#include <hip/hip_bf16.h>
#include <stdint.h>

#define SEQ 4096
#define DM  1024

typedef __attribute__((ext_vector_type(8))) short bf16x8;
typedef __attribute__((ext_vector_type(4))) float f32x4;

template <int V> struct Int { static constexpr int v = V; };

__device__ __forceinline__ short f2bf(float f) {
  union { float f; unsigned int i; } x; x.f = f;
  unsigned int r = x.i + 0x7FFFu + ((x.i >> 16) & 1u);
  return (short)(r >> 16);
}
__device__ __forceinline__ float bf2f(short s) {
  union { unsigned int i; float f; } u;
  u.i = ((unsigned int)(unsigned short)s) << 16;
  return u.f;
}

__device__ __forceinline__ void gload16(const short* g, short* l) {
  __builtin_amdgcn_global_load_lds(
      (const __attribute__((address_space(1))) unsigned int*)g,
      (__attribute__((address_space(3))) unsigned int*)l, 16, 0, 0);
}

__device__ __forceinline__ float wave_max(float v) {
#pragma unroll
  for (int o = 32; o; o >>= 1) v = fmaxf(v, __shfl_xor(v, o));
  return v;
}
__device__ __forceinline__ float wave_sum(float v) {
#pragma unroll
  for (int o = 32; o; o >>= 1) v += __shfl_xor(v, o);
  return v;
}

#define BARRIER() do { asm volatile("" ::: "memory"); \
  __builtin_amdgcn_s_barrier(); asm volatile("" ::: "memory"); } while (0)
#define MF(a, b, c) __builtin_amdgcn_mfma_f32_16x16x32_bf16(a, b, c, 0, 0, 0)

// ---------------------------------------------------------------------------
// 256x256-tile 8-phase bf16 GEMM: C[M,N] = A[M,K] * B[N,K]^T
// 8 waves (2M x 4N), BK=64, 128 KiB LDS (2 buf x {A0,A1,B0,B1} x 16 KiB).
// LDS swizzle (3-bit): byte ^= ((byte>>7)&7)<<4 — spreads the 16 rows a
// quarter-wave reads across all 8 16B-slots of a 128B row (2 lanes/slot =
// conflict-free for ds_read_b128). Same involution pre-applied to the
// global source address for the linear-dest global_load_lds.
// One half-tile staged per phase; counted vmcnt(4) at phases 4 & 8
// (ledger: 12 outstanding -> drain the 8 forming the buffer consumed next).
// EPI: 0 = plain bf16 out, 1 = +bias[col] bf16 out, 2 = *scale bf16 out
// split-K: grid = ntm*ntn*nsplit; split s reads K-range [s*Ksplit,(s+1)*Ksplit)
//          and writes C + s*csplit.
// ---------------------------------------------------------------------------
template <int EPI>
__global__ __launch_bounds__(512, 2) void gemm8(
    const short* __restrict__ A, const short* __restrict__ B,
    short* __restrict__ C, const float* __restrict__ bias,
    int Ksplit, int lda, int ldb, int ldc,
    float scale, int ntm, int ntn, long csplit) {
  __shared__ short lds[2][4][8192];  // [buf][A0,A1,B0,B1][128 rows x 64 k]
  const int tid = threadIdx.x;
  const int lane = tid & 63;
  const int wid = tid >> 6;   // 0..7
  const int wr = wid >> 2;    // 0,1  -> A slot / output row half
  const int wc = wid & 3;     // 0..3 -> 64-col group
  const int bid = blockIdx.x, nwg = gridDim.x;
  int wg = (bid & 7) * (nwg >> 3) + (bid >> 3);  // XCD-chunked swizzle
  const int tpg = ntm * ntn;
  const int split = wg / tpg;
  wg -= split * tpg;
  const int m0 = (wg / ntn) * 256;
  const int n0 = (wg % ntn) * 256;
  const short* Ab = A + (long)split * Ksplit;
  const short* Bb = B + (long)split * Ksplit;
  short* Co = C + (long)split * csplit;

  // staging: thread t fills half-tile bytes [t*16, t*16+16) linearly; source
  // address pre-swizzled with the involution swz(b) = b ^ (((b>>7)&7)<<4).
  const int o0 = tid * 16;
  const int oo = o0 ^ (((o0 >> 7) & 7) << 4);
  const int sr0 = oo >> 7;           // source row 0..63
  const int sc0 = (oo & 127) >> 1;   // source col in shorts (8-mult)

  auto stA = [&](int buf, int h, int kt) {
    const short* g = Ab + (long)(m0 + h * 128 + sr0) * lda + kt * 64 + sc0;
    short* l = &lds[buf][h][0] + wid * 512;
    gload16(g, l);
    gload16(g + (long)64 * lda, l + 4096);
  };
  auto stB = [&](int buf, int h, int kt) {
    const short* g = Bb + (long)(n0 + h * 128 + sr0) * ldb + kt * 64 + sc0;
    short* l = &lds[buf][2 + h][0] + wid * 512;
    gload16(g, l);
    gload16(g + (long)64 * ldb, l + 4096);
  };

  const int ll = lane & 15, lh = lane >> 4;
  // fragment reads: short-offset XOR (r&7)<<3 == byte XOR (r&7)<<4
  auto ldaf = [&](int buf, int c, int mm, int kk) {
    const int r = c * 32 + mm * 16 + ll;
    const int off = (r * 64 + kk * 32 + lh * 8) ^ ((r & 7) << 3);
    return *(const bf16x8*)(&lds[buf][wr][0] + off);
  };
  auto ldbf = [&](int buf, int n, int kk) {
    const int r = (wc & 1) * 64 + n * 16 + ll;
    const int off = (r * 64 + kk * 32 + lh * 8) ^ ((r & 7) << 3);
    return *(const bf16x8*)(&lds[buf][2 + (wc >> 1)][0] + off);
  };

  f32x4 acc[8][4];
#pragma unroll
  for (int i = 0; i < 8; i++)
#pragma unroll
    for (int j = 0; j < 4; j++) acc[i][j] = (f32x4){0.f, 0.f, 0.f, 0.f};
  bf16x8 Bf[4][2];

  const int NT = Ksplit >> 6;  // even for all call sites
  // prologue: B(0,*,0), A(0,*,0), B(1,*,1) = 12 loads; vmcnt(4) drains buf0.
  stB(0, 0, 0); stB(0, 1, 0);
  stA(0, 0, 0); stA(0, 1, 0);
  stB(1, 0, 1); stB(1, 1, 1);
  asm volatile("s_waitcnt vmcnt(4)" ::: "memory");
  BARRIER();

  auto phase = [&](auto BUF, auto CC, auto LB, auto&& stg, auto&& tail) {
    constexpr int buf = decltype(BUF)::v;
    constexpr int c = decltype(CC)::v;
    if constexpr (decltype(LB)::v != 0) {
#pragma unroll
      for (int n = 0; n < 4; n++) {
        Bf[n][0] = ldbf(buf, n, 0);
        Bf[n][1] = ldbf(buf, n, 1);
      }
    }
    bf16x8 a00 = ldaf(buf, c, 0, 0), a01 = ldaf(buf, c, 0, 1);
    bf16x8 a10 = ldaf(buf, c, 1, 0), a11 = ldaf(buf, c, 1, 1);
    stg();
    BARRIER();
    __builtin_amdgcn_s_setprio(1);
#pragma unroll
    for (int n = 0; n < 4; n++) {
      acc[2 * c][n] = MF(a00, Bf[n][0], acc[2 * c][n]);
      acc[2 * c][n] = MF(a01, Bf[n][1], acc[2 * c][n]);
      acc[2 * c + 1][n] = MF(a10, Bf[n][0], acc[2 * c + 1][n]);
      acc[2 * c + 1][n] = MF(a11, Bf[n][1], acc[2 * c + 1][n]);
    }
    __builtin_amdgcn_s_setprio(0);
    tail();
    BARRIER();
  };

  for (int t = 0; t < NT; t += 2) {
    const bool nl = (t + 2 < NT);
    // phases 1-4: tile t (buf0); stage A(1,*,t+1), B(0,*,t+2)
    phase(Int<0>{}, Int<0>{}, Int<1>{}, [&] { stA(1, 0, t + 1); }, [] {});
    phase(Int<0>{}, Int<1>{}, Int<0>{}, [&] { stA(1, 1, t + 1); }, [] {});
    phase(Int<0>{}, Int<2>{}, Int<0>{}, [&] { if (nl) stB(0, 0, t + 2); },
          [] {});
    phase(Int<0>{}, Int<3>{}, Int<0>{}, [&] { if (nl) stB(0, 1, t + 2); },
          [&] {
            if (nl) { asm volatile("s_waitcnt vmcnt(4)" ::: "memory"); }
            else    { asm volatile("s_waitcnt vmcnt(0)" ::: "memory"); }
          });
    // phases 5-8: tile t+1 (buf1); stage A(0,*,t+2), B(1,*,t+3)
    phase(Int<1>{}, Int<0>{}, Int<1>{}, [&] { if (nl) stA(0, 0, t + 2); },
          [] {});
    phase(Int<1>{}, Int<1>{}, Int<0>{}, [&] { if (nl) stA(0, 1, t + 2); },
          [] {});
    phase(Int<1>{}, Int<2>{}, Int<0>{}, [&] { if (nl) stB(1, 0, t + 3); },
          [] {});
    phase(Int<1>{}, Int<3>{}, Int<0>{}, [&] { if (nl) stB(1, 1, t + 3); },
          [&] {
            if (nl) { asm volatile("s_waitcnt vmcnt(4)" ::: "memory"); }
            else    { asm volatile("s_waitcnt vmcnt(0)" ::: "memory"); }
          });
  }

  // epilogue: wave writes 128x64 at (m0 + wr*128, n0 + wc*64)
  const int rb = m0 + wr * 128 + lh * 4;
  const int cb0 = n0 + wc * 64 + ll;
#pragma unroll
  for (int mi = 0; mi < 8; mi++) {
#pragma unroll
    for (int n = 0; n < 4; n++) {
      const int col = cb0 + n * 16;
      float bv = 0.f;
      if (EPI == 1) bv = bias[col];
#pragma unroll
      for (int r = 0; r < 4; r++) {
        const int row = rb + mi * 16 + r;
        const long off = (long)row * ldc + col;
        float v = acc[mi][n][r];
        if (EPI == 1) v += bv;
        if (EPI == 2) v *= scale;
        Co[off] = f2bf(v);
      }
    }
  }
}

// ---------------------------------------------------------------------------

__global__ __launch_bounds__(256) void cvt_f32_to_bf16(
    const float* __restrict__ in, short* __restrict__ out, int n4) {
  int i = blockIdx.x * 256 + threadIdx.x;
  if (i < n4) {
    float4 f = ((const float4*)in)[i];
    short4 o;
    o.x = f2bf(f.x); o.y = f2bf(f.y); o.z = f2bf(f.z); o.w = f2bf(f.w);
    ((short4*)out)[i] = o;
  }
}

// in[R][C] fp32 -> out[C][R] bf16
__global__ void transpose_w(const float* __restrict__ in,
                            short* __restrict__ out, int R, int C) {
  __shared__ float tile[32][33];
  const int bx = blockIdx.x * 32;
  const int by = blockIdx.y * 32;
  const int tx = threadIdx.x, ty = threadIdx.y;
#pragma unroll
  for (int i = 0; i < 32; i += 8)
    tile[ty + i][tx] = in[(long)(by + ty + i) * C + bx + tx];
  __syncthreads();
#pragma unroll
  for (int i = 0; i < 32; i += 8)
    out[(long)(bx + ty + i) * R + by + tx] = f2bf(tile[tx][ty + i]);
}

// in[R][C] bf16 (row stride ldin) -> out[C][R] bf16
__global__ void transpose_b_ld(const short* __restrict__ in,
                               short* __restrict__ out, int R, int C, int ldin) {
  __shared__ short tile[32][33];
  const int bx = blockIdx.x * 32;
  const int by = blockIdx.y * 32;
  const int tx = threadIdx.x, ty = threadIdx.y;
#pragma unroll
  for (int i = 0; i < 32; i += 8)
    tile[ty + i][tx] = in[(long)(by + ty + i) * ldin + bx + tx];
  __syncthreads();
#pragma unroll
  for (int i = 0; i < 32; i += 8)
    out[(long)(bx + ty + i) * R + by + tx] = tile[tx][ty + i];
}

// row softmax over scaled bf16 scores; mask (int32, nonzero = drop) applied
// here (-inf before max) so the GEMM epilogue stays clean.
__global__ __launch_bounds__(256) void softmax_rows(const short* __restrict__ Sb,
                                                    const int* __restrict__ mask,
                                                    short* __restrict__ Pb) {
  const long row = blockIdx.x;
  const bf16x8* src = (const bf16x8*)(Sb + row * SEQ);
  const int* mrow = mask + row * (long)SEQ;
  bf16x8* dst = (bf16x8*)(Pb + row * SEQ);
  const int tid = threadIdx.x;
  const int wid = tid >> 6, lane = tid & 63;
  bf16x8 a = src[tid], b = src[tid + 256];
  int4 ma0 = *(const int4*)(mrow + tid * 8);
  int4 ma1 = *(const int4*)(mrow + tid * 8 + 4);
  int4 mb0 = *(const int4*)(mrow + 2048 + tid * 8);
  int4 mb1 = *(const int4*)(mrow + 2048 + tid * 8 + 4);
  float v[16];
#pragma unroll
  for (int j = 0; j < 8; j++) { v[j] = bf2f(a[j]); v[8 + j] = bf2f(b[j]); }
  const int* mm0 = (const int*)&ma0;
  const int* mm1 = (const int*)&ma1;
  const int* mm2 = (const int*)&mb0;
  const int* mm3 = (const int*)&mb1;
#pragma unroll
  for (int j = 0; j < 4; j++) {
    if (mm0[j]) v[j] = -INFINITY;
    if (mm1[j]) v[4 + j] = -INFINITY;
    if (mm2[j]) v[8 + j] = -INFINITY;
    if (mm3[j]) v[12 + j] = -INFINITY;
  }
  float mx = -INFINITY;
#pragma unroll
  for (int j = 0; j < 16; j++) mx = fmaxf(mx, v[j]);
  mx = wave_max(mx);
  __shared__ float red[4];
  if (lane == 0) red[wid] = mx;
  __syncthreads();
  mx = fmaxf(fmaxf(red[0], red[1]), fmaxf(red[2], red[3]));
  float sum = 0.f;
#pragma unroll
  for (int j = 0; j < 16; j++) {
    v[j] = __expf(v[j] - mx);
    sum += v[j];
  }
  sum = wave_sum(sum);
  __shared__ float red2[4];
  if (lane == 0) red2[wid] = sum;
  __syncthreads();
  sum = red2[0] + red2[1] + red2[2] + red2[3];
  const float inv = 1.0f / sum;
  bf16x8 o0, o1;
#pragma unroll
  for (int j = 0; j < 8; j++) {
    o0[j] = f2bf(v[j] * inv);
    o1[j] = f2bf(v[8 + j] * inv);
  }
  dst[tid] = o0;
  dst[tid + 256] = o1;
}

// attention fp32 output = expand of bf16 probs
__global__ __launch_bounds__(256) void expand_bf16_f32(
    const short* __restrict__ in, float* __restrict__ out) {
  long i = (long)blockIdx.x * 256 + threadIdx.x;
  bf16x8 a = ((const bf16x8*)in)[i];
  float4 lo, hi;
  lo.x = bf2f(a[0]); lo.y = bf2f(a[1]); lo.z = bf2f(a[2]); lo.w = bf2f(a[3]);
  hi.x = bf2f(a[4]); hi.y = bf2f(a[5]); hi.z = bf2f(a[6]); hi.w = bf2f(a[7]);
  ((float4*)out)[2 * i] = lo;
  ((float4*)out)[2 * i + 1] = hi;
}

// context = sum of 4 AV partials + x -> bf16
__global__ __launch_bounds__(256) void reduce_ctx4(
    const short* __restrict__ p, const float* __restrict__ x,
    short* __restrict__ cb) {
  const long i = (long)blockIdx.x * 256 + threadIdx.x;
  bf16x8 a = ((const bf16x8*)p)[i];
  bf16x8 b = ((const bf16x8*)(p + 4194304))[i];
  bf16x8 c = ((const bf16x8*)(p + 8388608))[i];
  bf16x8 d = ((const bf16x8*)(p + 12582912))[i];
  float4 x0 = ((const float4*)x)[2 * i];
  float4 x1 = ((const float4*)x)[2 * i + 1];
  float xs[8] = {x0.x, x0.y, x0.z, x0.w, x1.x, x1.y, x1.z, x1.w};
  bf16x8 o;
#pragma unroll
  for (int j = 0; j < 8; j++)
    o[j] = f2bf(bf2f(a[j]) + bf2f(b[j]) + bf2f(c[j]) + bf2f(d[j]) + xs[j]);
  ((bf16x8*)cb)[i] = o;
}

// LayerNorm fused with the 4-way out-proj split reduce + bias.
__global__ __launch_bounds__(256) void ln4(
    const short* __restrict__ ph, const float* __restrict__ bo,
    const float* __restrict__ gamma, const float* __restrict__ beta,
    float* __restrict__ out) {
  const long row = blockIdx.x;
  const int tid = threadIdx.x;
  const int wid = tid >> 6, lane = tid & 63;
  const long base = row * DM + tid * 4;
  short4 p0 = *(const short4*)(ph + base);
  short4 p1 = *(const short4*)(ph + 4194304 + base);
  short4 p2 = *(const short4*)(ph + 8388608 + base);
  short4 p3 = *(const short4*)(ph + 12582912 + base);
  float4 bb = *(const float4*)(bo + tid * 4);
  float v[4];
  v[0] = bf2f(p0.x) + bf2f(p1.x) + bf2f(p2.x) + bf2f(p3.x) + bb.x;
  v[1] = bf2f(p0.y) + bf2f(p1.y) + bf2f(p2.y) + bf2f(p3.y) + bb.y;
  v[2] = bf2f(p0.z) + bf2f(p1.z) + bf2f(p2.z) + bf2f(p3.z) + bb.z;
  v[3] = bf2f(p0.w) + bf2f(p1.w) + bf2f(p2.w) + bf2f(p3.w) + bb.w;
  float s = v[0] + v[1] + v[2] + v[3];
  s = wave_sum(s);
  __shared__ float red[4];
  if (lane == 0) red[wid] = s;
  __syncthreads();
  const float mu = (red[0] + red[1] + red[2] + red[3]) * (1.f / DM);
  float var = 0.f;
#pragma unroll
  for (int j = 0; j < 4; j++) {
    float d = v[j] - mu;
    var += d * d;
  }
  var = wave_sum(var);
  __shared__ float red2[4];
  if (lane == 0) red2[wid] = var;
  __syncthreads();
  var = (red2[0] + red2[1] + red2[2] + red2[3]) * (1.f / DM);
  const float inv = rsqrtf(var + 1e-5f);
  float4 g = *(const float4*)(gamma + tid * 4);
  float4 be = *(const float4*)(beta + tid * 4);
  float4 o;
  o.x = (v[0] - mu) * inv * g.x + be.x;
  o.y = (v[1] - mu) * inv * g.y + be.y;
  o.z = (v[2] - mu) * inv * g.z + be.z;
  o.w = (v[3] - mu) * inv * g.w + be.w;
  *(float4*)(out + base) = o;
}

extern "C" void kernel_launch(void* const* d_in, const int* in_sizes, int n_in,
                              void* d_out, int out_size, void* d_ws,
                              size_t ws_size, hipStream_t stream) {
  const float* x    = (const float*)d_in[0];
  const int* mask   = (const int*)d_in[1];
  const float* wq   = (const float*)d_in[2];
  const float* bq   = (const float*)d_in[3];
  const float* wk   = (const float*)d_in[4];
  const float* bk   = (const float*)d_in[5];
  const float* wv   = (const float*)d_in[6];
  const float* bv   = (const float*)d_in[7];
  const float* wo   = (const float*)d_in[8];
  const float* bo   = (const float*)d_in[9];
  const float* gamma = (const float*)d_in[10];
  const float* beta  = (const float*)d_in[11];

  float* out  = (float*)d_out;             // final output [4096*1024] fp32
  float* attn = out + 4194304;             // attention [4096*4096] fp32
  short* Sb   = (short*)attn;              // scaled bf16 scores (32 MiB, dead after softmax)
  short* pav  = (short*)attn;              // 4 AV partials (32 MiB, over Sb)
  short* ph   = (short*)(attn + 8388608);  // 4 out-proj partials (32 MiB)
  short* cbuf = (short*)out;               // context bf16 (8 MiB, dead before LN writes)

  // ws (MiB): wqkvT[0,6) woT[6,8) xb[8,16) qkv[16,40) vT[40,48) bqkv[48,+12K)
  //           attnb[8,40) aliases xb+qkv once both are dead
  char* w = (char*)d_ws;
  short* wqkvT = (short*)(w + 0);
  short* woT   = (short*)(w + 6291456);
  short* xb    = (short*)(w + 8388608);
  short* qkv   = (short*)(w + 16777216);
  short* attnb = (short*)(w + 8388608);
  short* vT    = (short*)(w + 41943040);
  float* bqkv  = (float*)(w + 50331648);

  // ---- prep ----
  cvt_f32_to_bf16<<<4096, 256, 0, stream>>>(x, xb, 1048576);
  dim3 tb(32, 8);
  transpose_w<<<dim3(32, 32), tb, 0, stream>>>(wq, wqkvT, 1024, 1024);
  transpose_w<<<dim3(32, 32), tb, 0, stream>>>(wk, wqkvT + 1048576, 1024, 1024);
  transpose_w<<<dim3(32, 32), tb, 0, stream>>>(wv, wqkvT + 2097152, 1024, 1024);
  transpose_w<<<dim3(32, 32), tb, 0, stream>>>(wo, woT, 1024, 1024);
  hipMemcpyAsync(bqkv, bq, 4096, hipMemcpyDeviceToDevice, stream);
  hipMemcpyAsync(bqkv + 1024, bk, 4096, hipMemcpyDeviceToDevice, stream);
  hipMemcpyAsync(bqkv + 2048, bv, 4096, hipMemcpyDeviceToDevice, stream);

  // ---- qkv = x @ [wq|wk|wv] + b : M=4096 N=3072 K=1024, 192 blocks ----
  gemm8<1><<<192, 512, 0, stream>>>(xb, wqkvT, qkv, bqkv,
                                    1024, 1024, 1024, 3072, 1.f, 16, 12, 0);

  // v^T [1024][4096] from qkv's v-part
  transpose_b_ld<<<dim3(32, 128), tb, 0, stream>>>(qkv + 2048, vT, 4096, 1024, 3072);

  // ---- scores: bf16 (q k^T)/8 -> Sb (mask applied in softmax) ----
  gemm8<2><<<256, 512, 0, stream>>>(qkv, qkv + 1024, Sb, nullptr,
                                    1024, 3072, 3072, 4096, 0.125f, 16, 16, 0);

  // ---- softmax (+mask) -> bf16 probs ----
  softmax_rows<<<SEQ, 256, 0, stream>>>(Sb, mask, attnb);

  // ---- AV split-K=4 -> 4 bf16 partials (over Sb region) : 256 blocks ----
  gemm8<0><<<256, 512, 0, stream>>>(attnb, vT, pav, nullptr,
                                    1024, 4096, 4096, 1024, 1.f, 16, 4,
                                    4194304L);

  // context = sum partials + x -> bf16
  reduce_ctx4<<<2048, 256, 0, stream>>>(pav, x, cbuf);

  // ---- out-proj split-K=4 -> 4 bf16 partials : 256 blocks ----
  gemm8<0><<<256, 512, 0, stream>>>(cbuf, woT, ph, nullptr,
                                    256, 1024, 1024, 1024, 1.f, 16, 4,
                                    4194304L);

  // ---- LayerNorm fused with partial-reduce + bias ----
  ln4<<<SEQ, 256, 0, stream>>>(ph, bo, gamma, beta, out);

  // ---- attention fp32 output (after everything that uses the attn region) --
  expand_bf16_f32<<<8192, 256, 0, stream>>>(attnb, attn);
}

// Round 6
// 206.884 us; speedup vs baseline: 1.3286x; 1.0345x over previous
//
#include <hip/hip_runtime.h>
#include <hip/hip_bf16.h>
#include <stdint.h>

#define SEQ 4096
#define DM  1024

typedef __attribute__((ext_vector_type(8))) short bf16x8;
typedef __attribute__((ext_vector_type(4))) float f32x4;

template <int V> struct Int { static constexpr int v = V; };

__device__ __forceinline__ short f2bf(float f) {
  union { float f; unsigned int i; } x; x.f = f;
  unsigned int r = x.i + 0x7FFFu + ((x.i >> 16) & 1u);
  return (short)(r >> 16);
}
__device__ __forceinline__ float bf2f(short s) {
  union { unsigned int i; float f; } u;
  u.i = ((unsigned int)(unsigned short)s) << 16;
  return u.f;
}

__device__ __forceinline__ void gload16(const short* g, short* l) {
  __builtin_amdgcn_global_load_lds(
      (const __attribute__((address_space(1))) unsigned int*)g,
      (__attribute__((address_space(3))) unsigned int*)l, 16, 0, 0);
}

__device__ __forceinline__ float wave_max(float v) {
#pragma unroll
  for (int o = 32; o; o >>= 1) v = fmaxf(v, __shfl_xor(v, o));
  return v;
}
__device__ __forceinline__ float wave_sum(float v) {
#pragma unroll
  for (int o = 32; o; o >>= 1) v += __shfl_xor(v, o);
  return v;
}

#define BARRIER() do { asm volatile("" ::: "memory"); \
  __builtin_amdgcn_s_barrier(); asm volatile("" ::: "memory"); } while (0)
#define MF(a, b, c) __builtin_amdgcn_mfma_f32_16x16x32_bf16(a, b, c, 0, 0, 0)

// ---------------------------------------------------------------------------
// 256x256-tile 8-phase bf16 GEMM: C[M,N] = A[M,K] * B[N,K]^T
// 8 waves (2M x 4N), BK=64, 128 KiB LDS (2 buf x {A0,A1,B0,B1} x 16 KiB).
// LDS swizzle (3-bit): byte ^= ((byte>>7)&7)<<4 (conflict-free ds_read_b128);
// same involution pre-applied to the global source for linear-dest gload_lds.
// Stage schedule (bunched for max drain-age; ledger verified):
//   P1: A(1,*,t+1)   P2: B(0,*,t+2)   P4-tail: vmcnt(4)  [drains prevB(1)+A(1)]
//   P5: A(0,*,t+2)   P6: B(1,*,t+3)   P8-tail: vmcnt(4)  [drains B(0)+A(0)]
// 12 outstanding at each wait; drained loads are >=3 phases old.
// Final iteration (nl=false): 8/0 outstanding -> vmcnt(0).
// EPI: 0 = plain bf16 out, 1 = +bias[col] bf16 out, 2 = *scale bf16 out
// split-K: grid = ntm*ntn*nsplit; split s reads K-range [s*Ksplit,(s+1)*Ksplit)
//          and writes C + s*csplit.
// ---------------------------------------------------------------------------
template <int EPI>
__global__ __launch_bounds__(512, 2) void gemm8(
    const short* __restrict__ A, const short* __restrict__ B,
    short* __restrict__ C, const float* __restrict__ bias,
    int Ksplit, int lda, int ldb, int ldc,
    float scale, int ntm, int ntn, long csplit) {
  __shared__ short lds[2][4][8192];  // [buf][A0,A1,B0,B1][128 rows x 64 k]
  const int tid = threadIdx.x;
  const int lane = tid & 63;
  const int wid = tid >> 6;   // 0..7
  const int wr = wid >> 2;    // 0,1  -> A half / output row half
  const int wc = wid & 3;     // 0..3 -> 64-col group
  const int bid = blockIdx.x, nwg = gridDim.x;
  int wg = (bid & 7) * (nwg >> 3) + (bid >> 3);  // XCD-chunked swizzle
  const int tpg = ntm * ntn;
  const int split = wg / tpg;
  wg -= split * tpg;
  const int m0 = (wg / ntn) * 256;
  const int n0 = (wg % ntn) * 256;
  const short* Ab = A + (long)split * Ksplit;
  const short* Bb = B + (long)split * Ksplit;
  short* Co = C + (long)split * csplit;

  // staging: thread t fills half-tile bytes [t*16, t*16+16) linearly; source
  // address pre-swizzled with the involution swz(b) = b ^ (((b>>7)&7)<<4).
  const int o0 = tid * 16;
  const int oo = o0 ^ (((o0 >> 7) & 7) << 4);
  const int sr0 = oo >> 7;           // source row 0..63
  const int sc0 = (oo & 127) >> 1;   // source col in shorts (8-mult)

  auto stA = [&](int buf, int h, int kt) {
    const short* g = Ab + (long)(m0 + h * 128 + sr0) * lda + kt * 64 + sc0;
    short* l = &lds[buf][h][0] + wid * 512;
    gload16(g, l);
    gload16(g + (long)64 * lda, l + 4096);
  };
  auto stB = [&](int buf, int h, int kt) {
    const short* g = Bb + (long)(n0 + h * 128 + sr0) * ldb + kt * 64 + sc0;
    short* l = &lds[buf][2 + h][0] + wid * 512;
    gload16(g, l);
    gload16(g + (long)64 * ldb, l + 4096);
  };

  const int ll = lane & 15, lh = lane >> 4;
  // fragment reads: short-offset XOR (r&7)<<3 == byte XOR (r&7)<<4
  auto ldaf = [&](int buf, int c, int mm, int kk) {
    const int r = c * 32 + mm * 16 + ll;
    const int off = (r * 64 + kk * 32 + lh * 8) ^ ((r & 7) << 3);
    return *(const bf16x8*)(&lds[buf][wr][0] + off);
  };
  auto ldbf = [&](int buf, int n, int kk) {
    const int r = (wc & 1) * 64 + n * 16 + ll;
    const int off = (r * 64 + kk * 32 + lh * 8) ^ ((r & 7) << 3);
    return *(const bf16x8*)(&lds[buf][2 + (wc >> 1)][0] + off);
  };

  f32x4 acc[8][4];
#pragma unroll
  for (int i = 0; i < 8; i++)
#pragma unroll
    for (int j = 0; j < 4; j++) acc[i][j] = (f32x4){0.f, 0.f, 0.f, 0.f};
  bf16x8 Bf[4][2];

  const int NT = Ksplit >> 6;  // even, >= 4 at all call sites
  // prologue: B(0,*,0), A(0,*,0), B(1,*,1) = 12 loads; vmcnt(4) drains buf0.
  stB(0, 0, 0); stB(0, 1, 0);
  stA(0, 0, 0); stA(0, 1, 0);
  stB(1, 0, 1); stB(1, 1, 1);
  asm volatile("s_waitcnt vmcnt(4)" ::: "memory");
  BARRIER();

  auto phase = [&](auto BUF, auto CC, auto LB, auto&& stg, auto&& tail) {
    constexpr int buf = decltype(BUF)::v;
    constexpr int c = decltype(CC)::v;
    if constexpr (decltype(LB)::v != 0) {
#pragma unroll
      for (int n = 0; n < 4; n++) {
        Bf[n][0] = ldbf(buf, n, 0);
        Bf[n][1] = ldbf(buf, n, 1);
      }
    }
    bf16x8 a00 = ldaf(buf, c, 0, 0), a01 = ldaf(buf, c, 0, 1);
    bf16x8 a10 = ldaf(buf, c, 1, 0), a11 = ldaf(buf, c, 1, 1);
    stg();
    BARRIER();
    __builtin_amdgcn_s_setprio(1);
#pragma unroll
    for (int n = 0; n < 4; n++) {
      acc[2 * c][n] = MF(a00, Bf[n][0], acc[2 * c][n]);
      acc[2 * c][n] = MF(a01, Bf[n][1], acc[2 * c][n]);
      acc[2 * c + 1][n] = MF(a10, Bf[n][0], acc[2 * c + 1][n]);
      acc[2 * c + 1][n] = MF(a11, Bf[n][1], acc[2 * c + 1][n]);
    }
    __builtin_amdgcn_s_setprio(0);
    tail();
    BARRIER();
  };

  for (int t = 0; t < NT; t += 2) {
    const bool nl = (t + 2 < NT);
    // phases 1-4: compute tile t (buf0)
    phase(Int<0>{}, Int<0>{}, Int<1>{},
          [&] { stA(1, 0, t + 1); stA(1, 1, t + 1); }, [] {});
    phase(Int<0>{}, Int<1>{}, Int<0>{},
          [&] { if (nl) { stB(0, 0, t + 2); stB(0, 1, t + 2); } }, [] {});
    phase(Int<0>{}, Int<2>{}, Int<0>{}, [] {}, [] {});
    phase(Int<0>{}, Int<3>{}, Int<0>{}, [] {}, [&] {
      if (nl) { asm volatile("s_waitcnt vmcnt(4)" ::: "memory"); }
      else    { asm volatile("s_waitcnt vmcnt(0)" ::: "memory"); }
    });
    // phases 5-8: compute tile t+1 (buf1)
    phase(Int<1>{}, Int<0>{}, Int<1>{},
          [&] { if (nl) { stA(0, 0, t + 2); stA(0, 1, t + 2); } }, [] {});
    phase(Int<1>{}, Int<1>{}, Int<0>{},
          [&] { if (nl) { stB(1, 0, t + 3); stB(1, 1, t + 3); } }, [] {});
    phase(Int<1>{}, Int<2>{}, Int<0>{}, [] {}, [] {});
    phase(Int<1>{}, Int<3>{}, Int<0>{}, [] {}, [&] {
      if (nl) { asm volatile("s_waitcnt vmcnt(4)" ::: "memory"); }
      else    { asm volatile("s_waitcnt vmcnt(0)" ::: "memory"); }
    });
  }

  // epilogue: wave writes 128x64 at (m0 + wr*128, n0 + wc*64)
  const int rb = m0 + wr * 128 + lh * 4;
  const int cb0 = n0 + wc * 64 + ll;
#pragma unroll
  for (int mi = 0; mi < 8; mi++) {
#pragma unroll
    for (int n = 0; n < 4; n++) {
      const int col = cb0 + n * 16;
      float bv = 0.f;
      if (EPI == 1) bv = bias[col];
#pragma unroll
      for (int r = 0; r < 4; r++) {
        const int row = rb + mi * 16 + r;
        const long off = (long)row * ldc + col;
        float v = acc[mi][n][r];
        if (EPI == 1) v += bv;
        if (EPI == 2) v *= scale;
        Co[off] = f2bf(v);
      }
    }
  }
}

// ---------------------------------------------------------------------------

__global__ __launch_bounds__(256) void cvt_f32_to_bf16(
    const float* __restrict__ in, short* __restrict__ out, int n4) {
  int i = blockIdx.x * 256 + threadIdx.x;
  if (i < n4) {
    float4 f = ((const float4*)in)[i];
    short4 o;
    o.x = f2bf(f.x); o.y = f2bf(f.y); o.z = f2bf(f.z); o.w = f2bf(f.w);
    ((short4*)out)[i] = o;
  }
}

// four 1024x1024 fp32 -> bf16 transposes in one launch (z picks the matrix)
__global__ void transpose_w4(const float* __restrict__ s0,
                             const float* __restrict__ s1,
                             const float* __restrict__ s2,
                             const float* __restrict__ s3,
                             short* __restrict__ d0, short* __restrict__ d1,
                             short* __restrict__ d2, short* __restrict__ d3) {
  const int z = blockIdx.z;
  const float* in = z == 0 ? s0 : z == 1 ? s1 : z == 2 ? s2 : s3;
  short* out = z == 0 ? d0 : z == 1 ? d1 : z == 2 ? d2 : d3;
  __shared__ float tile[32][33];
  const int bx = blockIdx.x * 32;
  const int by = blockIdx.y * 32;
  const int tx = threadIdx.x, ty = threadIdx.y;
#pragma unroll
  for (int i = 0; i < 32; i += 8)
    tile[ty + i][tx] = in[(long)(by + ty + i) * 1024 + bx + tx];
  __syncthreads();
#pragma unroll
  for (int i = 0; i < 32; i += 8)
    out[(long)(bx + ty + i) * 1024 + by + tx] = f2bf(tile[tx][ty + i]);
}

// in[R][C] bf16 (row stride ldin) -> out[C][R] bf16
__global__ void transpose_b_ld(const short* __restrict__ in,
                               short* __restrict__ out, int R, int C, int ldin) {
  __shared__ short tile[32][33];
  const int bx = blockIdx.x * 32;
  const int by = blockIdx.y * 32;
  const int tx = threadIdx.x, ty = threadIdx.y;
#pragma unroll
  for (int i = 0; i < 32; i += 8)
    tile[ty + i][tx] = in[(long)(by + ty + i) * ldin + bx + tx];
  __syncthreads();
#pragma unroll
  for (int i = 0; i < 32; i += 8)
    out[(long)(bx + ty + i) * R + by + tx] = tile[tx][ty + i];
}

// bqkv = [bq | bk | bv] (replaces 3 SDMA memcpy nodes)
__global__ __launch_bounds__(256) void concat_bias(
    const float* __restrict__ bq, const float* __restrict__ bk,
    const float* __restrict__ bv, float* __restrict__ o) {
  int i = blockIdx.x * 256 + threadIdx.x;  // 0..3071
  float v = (i < 1024) ? bq[i] : (i < 2048 ? bk[i - 1024] : bv[i - 2048]);
  o[i] = v;
}

// row softmax over scaled bf16 scores; mask (int32, nonzero = drop) applied
// here (-inf before max) so the GEMM epilogue stays clean.
__global__ __launch_bounds__(256) void softmax_rows(const short* __restrict__ Sb,
                                                    const int* __restrict__ mask,
                                                    short* __restrict__ Pb) {
  const long row = blockIdx.x;
  const bf16x8* src = (const bf16x8*)(Sb + row * SEQ);
  const int* mrow = mask + row * (long)SEQ;
  bf16x8* dst = (bf16x8*)(Pb + row * SEQ);
  const int tid = threadIdx.x;
  const int wid = tid >> 6, lane = tid & 63;
  bf16x8 a = src[tid], b = src[tid + 256];
  int4 ma0 = *(const int4*)(mrow + tid * 8);
  int4 ma1 = *(const int4*)(mrow + tid * 8 + 4);
  int4 mb0 = *(const int4*)(mrow + 2048 + tid * 8);
  int4 mb1 = *(const int4*)(mrow + 2048 + tid * 8 + 4);
  float v[16];
#pragma unroll
  for (int j = 0; j < 8; j++) { v[j] = bf2f(a[j]); v[8 + j] = bf2f(b[j]); }
  const int* mm0 = (const int*)&ma0;
  const int* mm1 = (const int*)&ma1;
  const int* mm2 = (const int*)&mb0;
  const int* mm3 = (const int*)&mb1;
#pragma unroll
  for (int j = 0; j < 4; j++) {
    if (mm0[j]) v[j] = -INFINITY;
    if (mm1[j]) v[4 + j] = -INFINITY;
    if (mm2[j]) v[8 + j] = -INFINITY;
    if (mm3[j]) v[12 + j] = -INFINITY;
  }
  float mx = -INFINITY;
#pragma unroll
  for (int j = 0; j < 16; j++) mx = fmaxf(mx, v[j]);
  mx = wave_max(mx);
  __shared__ float red[4];
  if (lane == 0) red[wid] = mx;
  __syncthreads();
  mx = fmaxf(fmaxf(red[0], red[1]), fmaxf(red[2], red[3]));
  float sum = 0.f;
#pragma unroll
  for (int j = 0; j < 16; j++) {
    v[j] = __expf(v[j] - mx);
    sum += v[j];
  }
  sum = wave_sum(sum);
  __shared__ float red2[4];
  if (lane == 0) red2[wid] = sum;
  __syncthreads();
  sum = red2[0] + red2[1] + red2[2] + red2[3];
  const float inv = 1.0f / sum;
  bf16x8 o0, o1;
#pragma unroll
  for (int j = 0; j < 8; j++) {
    o0[j] = f2bf(v[j] * inv);
    o1[j] = f2bf(v[8 + j] * inv);
  }
  dst[tid] = o0;
  dst[tid + 256] = o1;
}

// attention fp32 output = expand of bf16 probs
__global__ __launch_bounds__(256) void expand_bf16_f32(
    const short* __restrict__ in, float* __restrict__ out) {
  long i = (long)blockIdx.x * 256 + threadIdx.x;
  bf16x8 a = ((const bf16x8*)in)[i];
  float4 lo, hi;
  lo.x = bf2f(a[0]); lo.y = bf2f(a[1]); lo.z = bf2f(a[2]); lo.w = bf2f(a[3]);
  hi.x = bf2f(a[4]); hi.y = bf2f(a[5]); hi.z = bf2f(a[6]); hi.w = bf2f(a[7]);
  ((float4*)out)[2 * i] = lo;
  ((float4*)out)[2 * i + 1] = hi;
}

// context = sum of 4 AV partials + x -> bf16
__global__ __launch_bounds__(256) void reduce_ctx4(
    const short* __restrict__ p, const float* __restrict__ x,
    short* __restrict__ cb) {
  const long i = (long)blockIdx.x * 256 + threadIdx.x;
  bf16x8 a = ((const bf16x8*)p)[i];
  bf16x8 b = ((const bf16x8*)(p + 4194304))[i];
  bf16x8 c = ((const bf16x8*)(p + 8388608))[i];
  bf16x8 d = ((const bf16x8*)(p + 12582912))[i];
  float4 x0 = ((const float4*)x)[2 * i];
  float4 x1 = ((const float4*)x)[2 * i + 1];
  float xs[8] = {x0.x, x0.y, x0.z, x0.w, x1.x, x1.y, x1.z, x1.w};
  bf16x8 o;
#pragma unroll
  for (int j = 0; j < 8; j++)
    o[j] = f2bf(bf2f(a[j]) + bf2f(b[j]) + bf2f(c[j]) + bf2f(d[j]) + xs[j]);
  ((bf16x8*)cb)[i] = o;
}

// LayerNorm fused with the 4-way out-proj split reduce + bias.
__global__ __launch_bounds__(256) void ln4(
    const short* __restrict__ ph, const float* __restrict__ bo,
    const float* __restrict__ gamma, const float* __restrict__ beta,
    float* __restrict__ out) {
  const long row = blockIdx.x;
  const int tid = threadIdx.x;
  const int wid = tid >> 6, lane = tid & 63;
  const long base = row * DM + tid * 4;
  short4 p0 = *(const short4*)(ph + base);
  short4 p1 = *(const short4*)(ph + 4194304 + base);
  short4 p2 = *(const short4*)(ph + 8388608 + base);
  short4 p3 = *(const short4*)(ph + 12582912 + base);
  float4 bb = *(const float4*)(bo + tid * 4);
  float v[4];
  v[0] = bf2f(p0.x) + bf2f(p1.x) + bf2f(p2.x) + bf2f(p3.x) + bb.x;
  v[1] = bf2f(p0.y) + bf2f(p1.y) + bf2f(p2.y) + bf2f(p3.y) + bb.y;
  v[2] = bf2f(p0.z) + bf2f(p1.z) + bf2f(p2.z) + bf2f(p3.z) + bb.z;
  v[3] = bf2f(p0.w) + bf2f(p1.w) + bf2f(p2.w) + bf2f(p3.w) + bb.w;
  float s = v[0] + v[1] + v[2] + v[3];
  s = wave_sum(s);
  __shared__ float red[4];
  if (lane == 0) red[wid] = s;
  __syncthreads();
  const float mu = (red[0] + red[1] + red[2] + red[3]) * (1.f / DM);
  float var = 0.f;
#pragma unroll
  for (int j = 0; j < 4; j++) {
    float d = v[j] - mu;
    var += d * d;
  }
  var = wave_sum(var);
  __shared__ float red2[4];
  if (lane == 0) red2[wid] = var;
  __syncthreads();
  var = (red2[0] + red2[1] + red2[2] + red2[3]) * (1.f / DM);
  const float inv = rsqrtf(var + 1e-5f);
  float4 g = *(const float4*)(gamma + tid * 4);
  float4 be = *(const float4*)(beta + tid * 4);
  float4 o;
  o.x = (v[0] - mu) * inv * g.x + be.x;
  o.y = (v[1] - mu) * inv * g.y + be.y;
  o.z = (v[2] - mu) * inv * g.z + be.z;
  o.w = (v[3] - mu) * inv * g.w + be.w;
  *(float4*)(out + base) = o;
}

extern "C" void kernel_launch(void* const* d_in, const int* in_sizes, int n_in,
                              void* d_out, int out_size, void* d_ws,
                              size_t ws_size, hipStream_t stream) {
  const float* x    = (const float*)d_in[0];
  const int* mask   = (const int*)d_in[1];
  const float* wq   = (const float*)d_in[2];
  const float* bq   = (const float*)d_in[3];
  const float* wk   = (const float*)d_in[4];
  const float* bk   = (const float*)d_in[5];
  const float* wv   = (const float*)d_in[6];
  const float* bv   = (const float*)d_in[7];
  const float* wo   = (const float*)d_in[8];
  const float* bo   = (const float*)d_in[9];
  const float* gamma = (const float*)d_in[10];
  const float* beta  = (const float*)d_in[11];

  float* out  = (float*)d_out;             // final output [4096*1024] fp32
  float* attn = out + 4194304;             // attention [4096*4096] fp32
  short* Sb   = (short*)attn;              // scaled bf16 scores (32 MiB, dead after softmax)
  short* pav  = (short*)attn;              // 4 AV partials (32 MiB, over Sb)
  short* ph   = (short*)(attn + 8388608);  // 4 out-proj partials (32 MiB)
  short* cbuf = (short*)out;               // context bf16 (8 MiB, dead before LN writes)

  // ws (MiB): wqkvT[0,6) woT[6,8) xb[8,16) qkv[16,40) vT[40,48) bqkv[48,+12K)
  //           attnb[8,40) aliases xb+qkv once both are dead
  char* w = (char*)d_ws;
  short* wqkvT = (short*)(w + 0);
  short* woT   = (short*)(w + 6291456);
  short* xb    = (short*)(w + 8388608);
  short* qkv   = (short*)(w + 16777216);
  short* attnb = (short*)(w + 8388608);
  short* vT    = (short*)(w + 41943040);
  float* bqkv  = (float*)(w + 50331648);

  // ---- prep ----
  cvt_f32_to_bf16<<<4096, 256, 0, stream>>>(x, xb, 1048576);
  transpose_w4<<<dim3(32, 32, 4), dim3(32, 8), 0, stream>>>(
      wq, wk, wv, wo, wqkvT, wqkvT + 1048576, wqkvT + 2097152, woT);
  concat_bias<<<12, 256, 0, stream>>>(bq, bk, bv, bqkv);

  // ---- qkv = x @ [wq|wk|wv] + b : M=4096 N=3072 K=1024, 192 blocks ----
  gemm8<1><<<192, 512, 0, stream>>>(xb, wqkvT, qkv, bqkv,
                                    1024, 1024, 1024, 3072, 1.f, 16, 12, 0);

  // v^T [1024][4096] from qkv's v-part
  transpose_b_ld<<<dim3(32, 128), dim3(32, 8), 0, stream>>>(qkv + 2048, vT,
                                                            4096, 1024, 3072);

  // ---- scores: bf16 (q k^T)/8 -> Sb (mask applied in softmax) ----
  gemm8<2><<<256, 512, 0, stream>>>(qkv, qkv + 1024, Sb, nullptr,
                                    1024, 3072, 3072, 4096, 0.125f, 16, 16, 0);

  // ---- softmax (+mask) -> bf16 probs ----
  softmax_rows<<<SEQ, 256, 0, stream>>>(Sb, mask, attnb);

  // ---- AV split-K=4 -> 4 bf16 partials (over Sb region) : 256 blocks ----
  gemm8<0><<<256, 512, 0, stream>>>(attnb, vT, pav, nullptr,
                                    1024, 4096, 4096, 1024, 1.f, 16, 4,
                                    4194304L);

  // context = sum partials + x -> bf16
  reduce_ctx4<<<2048, 256, 0, stream>>>(pav, x, cbuf);

  // ---- out-proj split-K=4 -> 4 bf16 partials : 256 blocks ----
  gemm8<0><<<256, 512, 0, stream>>>(cbuf, woT, ph, nullptr,
                                    256, 1024, 1024, 1024, 1.f, 16, 4,
                                    4194304L);

  // ---- LayerNorm fused with partial-reduce + bias ----
  ln4<<<SEQ, 256, 0, stream>>>(ph, bo, gamma, beta, out);

  // ---- attention fp32 output (after everything that uses the attn region) --
  expand_bf16_f32<<<8192, 256, 0, stream>>>(attnb, attn);
}

// Round 7
// 196.759 us; speedup vs baseline: 1.3970x; 1.0515x over previous
//
#include <hip/hip_runtime.h>
#include <hip/hip_bf16.h>
#include <stdint.h>

#define SEQ 4096
#define DM  1024

typedef __attribute__((ext_vector_type(8))) short bf16x8;
typedef __attribute__((ext_vector_type(4))) float f32x4;

template <int V> struct Int { static constexpr int v = V; };

__device__ __forceinline__ short f2bf(float f) {
  union { float f; unsigned int i; } x; x.f = f;
  unsigned int r = x.i + 0x7FFFu + ((x.i >> 16) & 1u);
  return (short)(r >> 16);
}
__device__ __forceinline__ float bf2f(short s) {
  union { unsigned int i; float f; } u;
  u.i = ((unsigned int)(unsigned short)s) << 16;
  return u.f;
}

__device__ __forceinline__ void gload16(const short* g, short* l) {
  __builtin_amdgcn_global_load_lds(
      (const __attribute__((address_space(1))) unsigned int*)g,
      (__attribute__((address_space(3))) unsigned int*)l, 16, 0, 0);
}

__device__ __forceinline__ float wave_max(float v) {
#pragma unroll
  for (int o = 32; o; o >>= 1) v = fmaxf(v, __shfl_xor(v, o));
  return v;
}
__device__ __forceinline__ float wave_sum(float v) {
#pragma unroll
  for (int o = 32; o; o >>= 1) v += __shfl_xor(v, o);
  return v;
}

#define BARRIER() do { asm volatile("" ::: "memory"); \
  __builtin_amdgcn_s_barrier(); asm volatile("" ::: "memory"); } while (0)
#define MF(a, b, c) __builtin_amdgcn_mfma_f32_16x16x32_bf16(a, b, c, 0, 0, 0)

// ---------------------------------------------------------------------------
// 256x256-tile 8-phase bf16 GEMM: C[M,N] = A[M,K] * B[N,K]^T
// 8 waves (2M x 4N), BK=64, 128 KiB LDS (2 buf x {A0,A1,B0,B1} x 16 KiB).
// LDS swizzle (3-bit): byte ^= ((byte>>7)&7)<<4 (conflict-free ds_read_b128,
// verified 0 conflicts); same involution pre-applied to the gload source.
// Sync structure (hazard-minimal): ONE barrier per phase except P1/P5
// (boundary barrier serves), i.e. 8 barriers per 2-tile pair. True hazards
// are only at buffer switches: the boundary {vmcnt; barrier} proves (a) the
// next buffer's stages landed and (b) every wave's reads of the dying buffer
// completed (lgkmcnt before its MFMA precedes the barrier).
// Stage placement (race-audited): P1: A(1,*,t+1) [buf1 A-slots, last read
// P8-prev, safe after boundary]; P3: B(0,*,t+2) [buf0 B-slots read only in
// P1, all waves past P2's barrier]; P5: A(0,*,t+2); P7: B(1,*,t+3).
// Ledger: 12 outstanding at each boundary; vmcnt(4) drains exactly the 8
// loads forming the buffer consumed next. Tail iterations: vmcnt(0).
// EPI: 0 = plain bf16, 1 = +bias[col], 2 = *scale,
//      3 = QKV mode: +bias; col<2048 -> C row-major; col>=2048 -> packed
//          transposed write to Cv (vT[col-2048][row], short4 over rows).
// split-K: grid = ntm*ntn*nsplit; split s reads K-range [s*Ksplit,(s+1)*Ksplit)
//          and writes C + s*csplit.
// L2 patch swizzle: per-XCD contiguous chunk arranged as (chunk/pc) x pc
//          tile patches (requires tpg % chunk == 0, pc | ntn, (chunk/pc) | ntm).
// ---------------------------------------------------------------------------
template <int EPI>
__global__ __launch_bounds__(512, 2) void gemm8(
    const short* __restrict__ A, const short* __restrict__ B,
    short* __restrict__ C, short* __restrict__ Cv,
    const float* __restrict__ bias, int Ksplit, int lda, int ldb, int ldc,
    int ldv, float scale, int ntm, int ntn, long csplit, int pc) {
  __shared__ short lds[2][4][8192];  // [buf][A0,A1,B0,B1][128 rows x 64 k]
  const int tid = threadIdx.x;
  const int lane = tid & 63;
  const int wid = tid >> 6;   // 0..7
  const int wr = wid >> 2;    // 0,1  -> A half / output row half
  const int wc = wid & 3;     // 0..3 -> 64-col group
  const int bid = blockIdx.x, nwg = gridDim.x;
  const int chunk = nwg >> 3;
  const int wl = (bid & 7) * chunk + (bid >> 3);  // contiguous per XCD
  const int tpg = ntm * ntn;
  const int split = wl / tpg;
  const int r0 = wl - split * tpg;
  const int q = r0 / chunk, i0 = r0 % chunk;
  const int npatch = ntn / pc;
  const int m0 = ((q / npatch) * (chunk / pc) + i0 / pc) * 256;
  const int n0 = ((q % npatch) * pc + i0 % pc) * 256;
  const short* Ab = A + (long)split * Ksplit;
  const short* Bb = B + (long)split * Ksplit;
  short* Co = C + (long)split * csplit;

  // staging: thread t fills half-tile bytes [t*16, t*16+16) linearly; source
  // address pre-swizzled with the involution swz(b) = b ^ (((b>>7)&7)<<4).
  const int o0 = tid * 16;
  const int oo = o0 ^ (((o0 >> 7) & 7) << 4);
  const int sr0 = oo >> 7;           // source row 0..63
  const int sc0 = (oo & 127) >> 1;   // source col in shorts (8-mult)

  auto stA = [&](int buf, int h, int kt) {
    const short* g = Ab + (long)(m0 + h * 128 + sr0) * lda + kt * 64 + sc0;
    short* l = &lds[buf][h][0] + wid * 512;
    gload16(g, l);
    gload16(g + (long)64 * lda, l + 4096);
  };
  auto stB = [&](int buf, int h, int kt) {
    const short* g = Bb + (long)(n0 + h * 128 + sr0) * ldb + kt * 64 + sc0;
    short* l = &lds[buf][2 + h][0] + wid * 512;
    gload16(g, l);
    gload16(g + (long)64 * ldb, l + 4096);
  };

  const int ll = lane & 15, lh = lane >> 4;
  // fragment reads: short-offset XOR (r&7)<<3 == byte XOR (r&7)<<4
  auto ldaf = [&](int buf, int c, int mm, int kk) {
    const int r = c * 32 + mm * 16 + ll;
    const int off = (r * 64 + kk * 32 + lh * 8) ^ ((r & 7) << 3);
    return *(const bf16x8*)(&lds[buf][wr][0] + off);
  };
  auto ldbf = [&](int buf, int n, int kk) {
    const int r = (wc & 1) * 64 + n * 16 + ll;
    const int off = (r * 64 + kk * 32 + lh * 8) ^ ((r & 7) << 3);
    return *(const bf16x8*)(&lds[buf][2 + (wc >> 1)][0] + off);
  };

  f32x4 acc[8][4];
#pragma unroll
  for (int i = 0; i < 8; i++)
#pragma unroll
    for (int j = 0; j < 4; j++) acc[i][j] = (f32x4){0.f, 0.f, 0.f, 0.f};
  bf16x8 Bf[4][2];

  const int NT = Ksplit >> 6;  // even, >= 4 at all call sites
  // prologue: B(0,*,0), A(0,*,0), B(1,*,1) = 12 loads; vmcnt(4) drains buf0.
  stB(0, 0, 0); stB(0, 1, 0);
  stA(0, 0, 0); stA(0, 1, 0);
  stB(1, 0, 1); stB(1, 1, 1);
  asm volatile("s_waitcnt vmcnt(4)" ::: "memory");
  BARRIER();

  // phase: [B-frag reads?] [A-frag reads] [stage hook] [barrier?] [16 MFMA]
  auto phase = [&](auto BUF, auto CC, auto LB, auto BARv, auto&& stg) {
    constexpr int buf = decltype(BUF)::v;
    constexpr int c = decltype(CC)::v;
    if constexpr (decltype(LB)::v != 0) {
#pragma unroll
      for (int n = 0; n < 4; n++) {
        Bf[n][0] = ldbf(buf, n, 0);
        Bf[n][1] = ldbf(buf, n, 1);
      }
    }
    bf16x8 a00 = ldaf(buf, c, 0, 0), a01 = ldaf(buf, c, 0, 1);
    bf16x8 a10 = ldaf(buf, c, 1, 0), a11 = ldaf(buf, c, 1, 1);
    stg();
    if constexpr (decltype(BARv)::v != 0) BARRIER();
    __builtin_amdgcn_s_setprio(1);
#pragma unroll
    for (int n = 0; n < 4; n++) {
      acc[2 * c][n] = MF(a00, Bf[n][0], acc[2 * c][n]);
      acc[2 * c][n] = MF(a01, Bf[n][1], acc[2 * c][n]);
      acc[2 * c + 1][n] = MF(a10, Bf[n][0], acc[2 * c + 1][n]);
      acc[2 * c + 1][n] = MF(a11, Bf[n][1], acc[2 * c + 1][n]);
    }
    __builtin_amdgcn_s_setprio(0);
  };

  for (int t = 0; t < NT; t += 2) {
    const bool nl = (t + 2 < NT);
    // group A: compute tile t (buf0)
    phase(Int<0>{}, Int<0>{}, Int<1>{}, Int<0>{},
          [&] { stA(1, 0, t + 1); stA(1, 1, t + 1); });
    phase(Int<0>{}, Int<1>{}, Int<0>{}, Int<1>{}, [] {});
    phase(Int<0>{}, Int<2>{}, Int<0>{}, Int<1>{},
          [&] { if (nl) { stB(0, 0, t + 2); stB(0, 1, t + 2); } });
    phase(Int<0>{}, Int<3>{}, Int<0>{}, Int<1>{}, [] {});
    // boundary into buf1
    if (nl) { asm volatile("s_waitcnt vmcnt(4)" ::: "memory"); }
    else    { asm volatile("s_waitcnt vmcnt(0)" ::: "memory"); }
    BARRIER();
    // group B: compute tile t+1 (buf1)
    phase(Int<1>{}, Int<0>{}, Int<1>{}, Int<0>{},
          [&] { if (nl) { stA(0, 0, t + 2); stA(0, 1, t + 2); } });
    phase(Int<1>{}, Int<1>{}, Int<0>{}, Int<1>{}, [] {});
    phase(Int<1>{}, Int<2>{}, Int<0>{}, Int<1>{},
          [&] { if (nl) { stB(1, 0, t + 3); stB(1, 1, t + 3); } });
    phase(Int<1>{}, Int<3>{}, Int<0>{}, Int<1>{}, [] {});
    // boundary into buf0 of next iteration (skip after the last tile)
    if (nl) {
      asm volatile("s_waitcnt vmcnt(4)" ::: "memory");
      BARRIER();
    }
  }

  // epilogue: wave writes 128x64 at (m0 + wr*128, n0 + wc*64)
  const int rb = m0 + wr * 128 + lh * 4;
  const int cb0 = n0 + wc * 64 + ll;
  if (EPI == 3 && n0 >= 2048) {
    // v-block: bias + packed transposed write to vT[col-2048][row]
#pragma unroll
    for (int mi = 0; mi < 8; mi++) {
#pragma unroll
      for (int n = 0; n < 4; n++) {
        const int col = cb0 + n * 16;
        const float bv = bias[col];
        short4 pk;
        pk.x = f2bf(acc[mi][n][0] + bv);
        pk.y = f2bf(acc[mi][n][1] + bv);
        pk.z = f2bf(acc[mi][n][2] + bv);
        pk.w = f2bf(acc[mi][n][3] + bv);
        *(short4*)(Cv + (long)(col - 2048) * ldv + rb + mi * 16) = pk;
      }
    }
    return;
  }
#pragma unroll
  for (int mi = 0; mi < 8; mi++) {
#pragma unroll
    for (int n = 0; n < 4; n++) {
      const int col = cb0 + n * 16;
      float bv = 0.f;
      if (EPI == 1 || EPI == 3) bv = bias[col];
#pragma unroll
      for (int r = 0; r < 4; r++) {
        const int row = rb + mi * 16 + r;
        const long off = (long)row * ldc + col;
        float v = acc[mi][n][r];
        if (EPI == 1 || EPI == 3) v += bv;
        if (EPI == 2) v *= scale;
        Co[off] = f2bf(v);
      }
    }
  }
}

// ---------------------------------------------------------------------------

__global__ __launch_bounds__(256) void cvt_f32_to_bf16(
    const float* __restrict__ in, short* __restrict__ out, int n4) {
  int i = blockIdx.x * 256 + threadIdx.x;
  if (i < n4) {
    float4 f = ((const float4*)in)[i];
    short4 o;
    o.x = f2bf(f.x); o.y = f2bf(f.y); o.z = f2bf(f.z); o.w = f2bf(f.w);
    ((short4*)out)[i] = o;
  }
}

// four 1024x1024 fp32 -> bf16 transposes in one launch (z picks the matrix)
__global__ void transpose_w4(const float* __restrict__ s0,
                             const float* __restrict__ s1,
                             const float* __restrict__ s2,
                             const float* __restrict__ s3,
                             short* __restrict__ d0, short* __restrict__ d1,
                             short* __restrict__ d2, short* __restrict__ d3) {
  const int z = blockIdx.z;
  const float* in = z == 0 ? s0 : z == 1 ? s1 : z == 2 ? s2 : s3;
  short* out = z == 0 ? d0 : z == 1 ? d1 : z == 2 ? d2 : d3;
  __shared__ float tile[32][33];
  const int bx = blockIdx.x * 32;
  const int by = blockIdx.y * 32;
  const int tx = threadIdx.x, ty = threadIdx.y;
#pragma unroll
  for (int i = 0; i < 32; i += 8)
    tile[ty + i][tx] = in[(long)(by + ty + i) * 1024 + bx + tx];
  __syncthreads();
#pragma unroll
  for (int i = 0; i < 32; i += 8)
    out[(long)(bx + ty + i) * 1024 + by + tx] = f2bf(tile[tx][ty + i]);
}

// bqkv = [bq | bk | bv]
__global__ __launch_bounds__(256) void concat_bias(
    const float* __restrict__ bq, const float* __restrict__ bk,
    const float* __restrict__ bv, float* __restrict__ o) {
  int i = blockIdx.x * 256 + threadIdx.x;  // 0..3071
  float v = (i < 1024) ? bq[i] : (i < 2048 ? bk[i - 1024] : bv[i - 2048]);
  o[i] = v;
}

// row softmax over scaled bf16 scores; mask (int32, nonzero = drop) applied
// here (-inf before max).
__global__ __launch_bounds__(256) void softmax_rows(const short* __restrict__ Sb,
                                                    const int* __restrict__ mask,
                                                    short* __restrict__ Pb) {
  const long row = blockIdx.x;
  const bf16x8* src = (const bf16x8*)(Sb + row * SEQ);
  const int* mrow = mask + row * (long)SEQ;
  bf16x8* dst = (bf16x8*)(Pb + row * SEQ);
  const int tid = threadIdx.x;
  const int wid = tid >> 6, lane = tid & 63;
  bf16x8 a = src[tid], b = src[tid + 256];
  int4 ma0 = *(const int4*)(mrow + tid * 8);
  int4 ma1 = *(const int4*)(mrow + tid * 8 + 4);
  int4 mb0 = *(const int4*)(mrow + 2048 + tid * 8);
  int4 mb1 = *(const int4*)(mrow + 2048 + tid * 8 + 4);
  float v[16];
#pragma unroll
  for (int j = 0; j < 8; j++) { v[j] = bf2f(a[j]); v[8 + j] = bf2f(b[j]); }
  const int* mm0 = (const int*)&ma0;
  const int* mm1 = (const int*)&ma1;
  const int* mm2 = (const int*)&mb0;
  const int* mm3 = (const int*)&mb1;
#pragma unroll
  for (int j = 0; j < 4; j++) {
    if (mm0[j]) v[j] = -INFINITY;
    if (mm1[j]) v[4 + j] = -INFINITY;
    if (mm2[j]) v[8 + j] = -INFINITY;
    if (mm3[j]) v[12 + j] = -INFINITY;
  }
  float mx = -INFINITY;
#pragma unroll
  for (int j = 0; j < 16; j++) mx = fmaxf(mx, v[j]);
  mx = wave_max(mx);
  __shared__ float red[4];
  if (lane == 0) red[wid] = mx;
  __syncthreads();
  mx = fmaxf(fmaxf(red[0], red[1]), fmaxf(red[2], red[3]));
  float sum = 0.f;
#pragma unroll
  for (int j = 0; j < 16; j++) {
    v[j] = __expf(v[j] - mx);
    sum += v[j];
  }
  sum = wave_sum(sum);
  __shared__ float red2[4];
  if (lane == 0) red2[wid] = sum;
  __syncthreads();
  sum = red2[0] + red2[1] + red2[2] + red2[3];
  const float inv = 1.0f / sum;
  bf16x8 o0, o1;
#pragma unroll
  for (int j = 0; j < 8; j++) {
    o0[j] = f2bf(v[j] * inv);
    o1[j] = f2bf(v[8 + j] * inv);
  }
  dst[tid] = o0;
  dst[tid + 256] = o1;
}

// attention fp32 output = expand of bf16 probs
__global__ __launch_bounds__(256) void expand_bf16_f32(
    const short* __restrict__ in, float* __restrict__ out) {
  long i = (long)blockIdx.x * 256 + threadIdx.x;
  bf16x8 a = ((const bf16x8*)in)[i];
  float4 lo, hi;
  lo.x = bf2f(a[0]); lo.y = bf2f(a[1]); lo.z = bf2f(a[2]); lo.w = bf2f(a[3]);
  hi.x = bf2f(a[4]); hi.y = bf2f(a[5]); hi.z = bf2f(a[6]); hi.w = bf2f(a[7]);
  ((float4*)out)[2 * i] = lo;
  ((float4*)out)[2 * i + 1] = hi;
}

// context = sum of 4 AV partials + x -> bf16
__global__ __launch_bounds__(256) void reduce_ctx4(
    const short* __restrict__ p, const float* __restrict__ x,
    short* __restrict__ cb) {
  const long i = (long)blockIdx.x * 256 + threadIdx.x;
  bf16x8 a = ((const bf16x8*)p)[i];
  bf16x8 b = ((const bf16x8*)(p + 4194304))[i];
  bf16x8 c = ((const bf16x8*)(p + 8388608))[i];
  bf16x8 d = ((const bf16x8*)(p + 12582912))[i];
  float4 x0 = ((const float4*)x)[2 * i];
  float4 x1 = ((const float4*)x)[2 * i + 1];
  float xs[8] = {x0.x, x0.y, x0.z, x0.w, x1.x, x1.y, x1.z, x1.w};
  bf16x8 o;
#pragma unroll
  for (int j = 0; j < 8; j++)
    o[j] = f2bf(bf2f(a[j]) + bf2f(b[j]) + bf2f(c[j]) + bf2f(d[j]) + xs[j]);
  ((bf16x8*)cb)[i] = o;
}

// LayerNorm fused with the 4-way out-proj split reduce + bias.
__global__ __launch_bounds__(256) void ln4(
    const short* __restrict__ ph, const float* __restrict__ bo,
    const float* __restrict__ gamma, const float* __restrict__ beta,
    float* __restrict__ out) {
  const long row = blockIdx.x;
  const int tid = threadIdx.x;
  const int wid = tid >> 6, lane = tid & 63;
  const long base = row * DM + tid * 4;
  short4 p0 = *(const short4*)(ph + base);
  short4 p1 = *(const short4*)(ph + 4194304 + base);
  short4 p2 = *(const short4*)(ph + 8388608 + base);
  short4 p3 = *(const short4*)(ph + 12582912 + base);
  float4 bb = *(const float4*)(bo + tid * 4);
  float v[4];
  v[0] = bf2f(p0.x) + bf2f(p1.x) + bf2f(p2.x) + bf2f(p3.x) + bb.x;
  v[1] = bf2f(p0.y) + bf2f(p1.y) + bf2f(p2.y) + bf2f(p3.y) + bb.y;
  v[2] = bf2f(p0.z) + bf2f(p1.z) + bf2f(p2.z) + bf2f(p3.z) + bb.z;
  v[3] = bf2f(p0.w) + bf2f(p1.w) + bf2f(p2.w) + bf2f(p3.w) + bb.w;
  float s = v[0] + v[1] + v[2] + v[3];
  s = wave_sum(s);
  __shared__ float red[4];
  if (lane == 0) red[wid] = s;
  __syncthreads();
  const float mu = (red[0] + red[1] + red[2] + red[3]) * (1.f / DM);
  float var = 0.f;
#pragma unroll
  for (int j = 0; j < 4; j++) {
    float d = v[j] - mu;
    var += d * d;
  }
  var = wave_sum(var);
  __shared__ float red2[4];
  if (lane == 0) red2[wid] = var;
  __syncthreads();
  var = (red2[0] + red2[1] + red2[2] + red2[3]) * (1.f / DM);
  const float inv = rsqrtf(var + 1e-5f);
  float4 g = *(const float4*)(gamma + tid * 4);
  float4 be = *(const float4*)(beta + tid * 4);
  float4 o;
  o.x = (v[0] - mu) * inv * g.x + be.x;
  o.y = (v[1] - mu) * inv * g.y + be.y;
  o.z = (v[2] - mu) * inv * g.z + be.z;
  o.w = (v[3] - mu) * inv * g.w + be.w;
  *(float4*)(out + base) = o;
}

extern "C" void kernel_launch(void* const* d_in, const int* in_sizes, int n_in,
                              void* d_out, int out_size, void* d_ws,
                              size_t ws_size, hipStream_t stream) {
  const float* x    = (const float*)d_in[0];
  const int* mask   = (const int*)d_in[1];
  const float* wq   = (const float*)d_in[2];
  const float* bq   = (const float*)d_in[3];
  const float* wk   = (const float*)d_in[4];
  const float* bk   = (const float*)d_in[5];
  const float* wv   = (const float*)d_in[6];
  const float* bv   = (const float*)d_in[7];
  const float* wo   = (const float*)d_in[8];
  const float* bo   = (const float*)d_in[9];
  const float* gamma = (const float*)d_in[10];
  const float* beta  = (const float*)d_in[11];

  float* out  = (float*)d_out;             // final output [4096*1024] fp32
  float* attn = out + 4194304;             // attention [4096*4096] fp32
  short* Sb   = (short*)attn;              // scaled bf16 scores (32 MiB, dead after softmax)
  short* pav  = (short*)attn;              // 4 AV partials (32 MiB, over Sb)
  short* ph   = (short*)(attn + 8388608);  // 4 out-proj partials (32 MiB)
  short* cbuf = (short*)out;               // context bf16 (8 MiB, dead before LN writes)

  // ws (MiB): wqkvT[0,6) woT[6,8) xb[8,16) qkv[16,40) vT[40,48) bqkv[48,+12K)
  //           attnb[8,40) aliases xb+qkv once both are dead
  char* w = (char*)d_ws;
  short* wqkvT = (short*)(w + 0);
  short* woT   = (short*)(w + 6291456);
  short* xb    = (short*)(w + 8388608);
  short* qkv   = (short*)(w + 16777216);
  short* attnb = (short*)(w + 8388608);
  short* vT    = (short*)(w + 41943040);
  float* bqkv  = (float*)(w + 50331648);

  // ---- prep ----
  cvt_f32_to_bf16<<<4096, 256, 0, stream>>>(x, xb, 1048576);
  transpose_w4<<<dim3(32, 32, 4), dim3(32, 8), 0, stream>>>(
      wq, wk, wv, wo, wqkvT, wqkvT + 1048576, wqkvT + 2097152, woT);
  concat_bias<<<12, 256, 0, stream>>>(bq, bk, bv, bqkv);

  // ---- qkv = x @ [wq|wk|wv] + b, v-part written transposed to vT ----
  gemm8<3><<<192, 512, 0, stream>>>(xb, wqkvT, qkv, vT, bqkv,
                                    1024, 1024, 1024, 3072, 4096, 1.f,
                                    16, 12, 0, 6);

  // ---- scores: bf16 (q k^T)/8 -> Sb (mask applied in softmax) ----
  gemm8<2><<<256, 512, 0, stream>>>(qkv, qkv + 1024, Sb, nullptr, nullptr,
                                    1024, 3072, 3072, 4096, 0, 0.125f,
                                    16, 16, 0, 8);

  // ---- softmax (+mask) -> bf16 probs ----
  softmax_rows<<<SEQ, 256, 0, stream>>>(Sb, mask, attnb);

  // ---- AV split-K=4 -> 4 bf16 partials (over Sb region) ----
  gemm8<0><<<256, 512, 0, stream>>>(attnb, vT, pav, nullptr, nullptr,
                                    1024, 4096, 4096, 1024, 0, 1.f,
                                    16, 4, 4194304L, 4);

  // context = sum partials + x -> bf16
  reduce_ctx4<<<2048, 256, 0, stream>>>(pav, x, cbuf);

  // ---- out-proj split-K=4 -> 4 bf16 partials ----
  gemm8<0><<<256, 512, 0, stream>>>(cbuf, woT, ph, nullptr, nullptr,
                                    256, 1024, 1024, 1024, 0, 1.f,
                                    16, 4, 4194304L, 4);

  // ---- LayerNorm fused with partial-reduce + bias ----
  ln4<<<SEQ, 256, 0, stream>>>(ph, bo, gamma, beta, out);

  // ---- attention fp32 output (after everything that uses the attn region) --
  expand_bf16_f32<<<8192, 256, 0, stream>>>(attnb, attn);
}